// Round 3
// baseline (279.789 us; speedup 1.0000x reference)
//
#include <hip/hip_runtime.h>
#include <stdint.h>

#define DEVINL __device__ __forceinline__

typedef __attribute__((ext_vector_type(8))) __bf16 bf16x8;
typedef __attribute__((ext_vector_type(4))) float f32x4;

// ---------- helpers ----------
DEVINL unsigned short f2bf(float f) {
  union { float f; unsigned int u; } v; v.f = f;
  unsigned int u = v.u;
  return (unsigned short)((u + 0x7fffu + ((u >> 16) & 1u)) >> 16);  // RNE
}

DEVINL float sigmoid_fast(float x) { return 1.f / (1.f + __expf(-x)); }

DEVINL float tanh_fast(float x) {
  x = fminf(15.f, fmaxf(-15.f, x));
  float e = __expf(2.f * x);
  return (e - 1.f) / (e + 1.f);
}

// async global->LDS 16B per lane; lds base wave-uniform, HW scatters lane i to base+i*16
#define GLD_LDS16(gptr, lptr)                                                  \
  __builtin_amdgcn_global_load_lds(                                            \
      (__attribute__((address_space(1))) void*)(gptr),                         \
      (__attribute__((address_space(3))) void*)(lptr), 16, 0, 0)

// XOR swizzle: LDS chunk (row, q') holds global chunk q' ^ ((row>>1)&3) of that row.
// For staging chunk index c (row=c>>2): source column-chunk = (c&3)^((c>>3)&3).
// Bijective within each 8-chunk group -> coverage identical to unswizzled.
DEVINL int swz_col(int c) { return ((c & 3) ^ ((c >> 3) & 3)) * 8; }

// ---------- prep: concat(obs, act) -> bf16 [B,544] ----------
__global__ void prep_input(const float* __restrict__ obs,
                           const float* __restrict__ act,
                           unsigned short* __restrict__ A0) {
  const int total = 32768 * 68;  // 16B chunks (8 bf16) per row: 68
  for (int c = blockIdx.x * blockDim.x + threadIdx.x; c < total;
       c += gridDim.x * blockDim.x) {
    const int b = c / 68, c8 = c % 68;
    const float* src = (c8 < 64) ? (obs + (size_t)b * 512 + c8 * 8)
                                 : (act + (size_t)b * 32 + (c8 - 64) * 8);
    float4 f0 = *(const float4*)src;
    float4 f1 = *(const float4*)(src + 4);
    unsigned short u[8] = {f2bf(f0.x), f2bf(f0.y), f2bf(f0.z), f2bf(f0.w),
                           f2bf(f1.x), f2bf(f1.y), f2bf(f1.z), f2bf(f1.w)};
    *(uint4*)(A0 + (size_t)b * 544 + c8 * 8) = *(uint4*)u;
  }
}

// ---------- prep: fp32 -> bf16 generic ----------
__global__ void cvt_bf16(const float* __restrict__ src,
                         unsigned short* __restrict__ dst, int n4) {
  for (int i = blockIdx.x * blockDim.x + threadIdx.x; i < n4;
       i += gridDim.x * blockDim.x) {
    float4 f = *(const float4*)(src + (size_t)i * 4);
    unsigned short u[4] = {f2bf(f.x), f2bf(f.y), f2bf(f.z), f2bf(f.w)};
    *(uint2*)(dst + (size_t)i * 4) = *(uint2*)u;
  }
}

// ---------- prep: hvec[j] = dot(W_hh[j,:], hid) + b_hh[j] + b_ih[j] ----------
__global__ void calc_hvec(const float* __restrict__ Whh,
                          const float* __restrict__ hid,
                          const float* __restrict__ bhh,
                          const float* __restrict__ bih,
                          float* __restrict__ hvec) {
  const int j = blockIdx.x * 4 + (threadIdx.x >> 6);
  const int lane = threadIdx.x & 63;
  const float* w = Whh + (size_t)j * 512;
  float s = 0.f;
  for (int k = lane; k < 512; k += 64) s += w[k] * hid[k];
  for (int off = 32; off; off >>= 1) s += __shfl_down(s, off, 64);
  if (lane == 0) hvec[j] = s + bhh[j] + bih[j];
}

// ---------- GEMM1: X = relu(A0 @ W1^T + b1), bf16 out ----------
__global__ __launch_bounds__(256, 2) void gemm1_relu(
    const unsigned short* __restrict__ A0,   // [32768,544] bf16
    const unsigned short* __restrict__ W1b,  // [512,544] bf16
    const float* __restrict__ b1,            // [512]
    unsigned short* __restrict__ X) {        // [32768,512] bf16
  constexpr int KT = 17, LD = 544;
  __shared__ __align__(16) unsigned short As[128 * 32];
  __shared__ __align__(16) unsigned short Bs[128 * 32];
  const int tid = threadIdx.x, wave = tid >> 6, lane = tid & 63;
  const int m0 = blockIdx.x * 128, n0 = blockIdx.y * 128;
  const int wr = (wave >> 1) * 64, wc = (wave & 1) * 64;
  f32x4 acc[4][4] = {};

  const int c0 = tid, c1 = tid + 256;  // chunk: row=c>>2, swizzled col
  const int s0 = swz_col(c0), s1 = swz_col(c1);
  for (int kt = 0; kt < KT; ++kt) {
    const int k0 = kt * 32;
    GLD_LDS16(A0 + (size_t)(m0 + (c0 >> 2)) * LD + k0 + s0, &As[wave * 512]);
    GLD_LDS16(A0 + (size_t)(m0 + (c1 >> 2)) * LD + k0 + s1, &As[2048 + wave * 512]);
    GLD_LDS16(W1b + (size_t)(n0 + (c0 >> 2)) * LD + k0 + s0, &Bs[wave * 512]);
    GLD_LDS16(W1b + (size_t)(n0 + (c1 >> 2)) * LD + k0 + s1, &Bs[2048 + wave * 512]);
    asm volatile("s_waitcnt vmcnt(0)" ::: "memory");
    __syncthreads();
    const int fr = lane & 15, q = lane >> 4;
    const int koff = (q ^ ((fr >> 1) & 3)) * 8;  // matches staging swizzle
    bf16x8 a[4], b[4];
#pragma unroll
    for (int i = 0; i < 4; ++i) a[i] = *(const bf16x8*)&As[(wr + i * 16 + fr) * 32 + koff];
#pragma unroll
    for (int j = 0; j < 4; ++j) b[j] = *(const bf16x8*)&Bs[(wc + j * 16 + fr) * 32 + koff];
#pragma unroll
    for (int i = 0; i < 4; ++i)
#pragma unroll
      for (int j = 0; j < 4; ++j)
        acc[i][j] = __builtin_amdgcn_mfma_f32_16x16x32_bf16(a[i], b[j], acc[i][j], 0, 0, 0);
    __syncthreads();
  }
  const int rbase = ((lane >> 4)) * 4, cn = lane & 15;
#pragma unroll
  for (int i = 0; i < 4; ++i)
#pragma unroll
    for (int j = 0; j < 4; ++j) {
      const int gn = n0 + wc + j * 16 + cn;
      const float bias = b1[gn];
#pragma unroll
      for (int r = 0; r < 4; ++r) {
        const int gm = m0 + wr + i * 16 + rbase + r;
        float v = acc[i][j][r] + bias;
        v = v > 0.f ? v : 0.f;
        X[(size_t)gm * 512 + gn] = f2bf(v);
      }
    }
}

// ---------- GEMM2 (4 gate quadrants) + LSTM epilogue ----------
__global__ __launch_bounds__(256, 2) void gemm2_lstm(
    const unsigned short* __restrict__ X,    // [32768,512] bf16
    const unsigned short* __restrict__ Wih,  // [2048,512] bf16
    const float* __restrict__ hvec,          // [2048]
    const float* __restrict__ cell,          // [512]
    unsigned short* __restrict__ H,          // [32768,512] bf16 out
    float* __restrict__ hlast,               // [512] fp32 out
    float* __restrict__ clast) {             // [512] fp32 out
  constexpr int KT = 16;
  __shared__ __align__(16) unsigned short As[128 * 32];
  __shared__ __align__(16) unsigned short Bs[4 * 32 * 32];
  const int tid = threadIdx.x, wave = tid >> 6, lane = tid & 63;
  const int m0 = blockIdx.x * 128;
  const int n0 = blockIdx.y * 32;            // quadrant-column tile
  const int wr = (wave >> 1) * 64, wc = (wave & 1) * 16;
  f32x4 acc[4][4] = {};                      // [row-tile][quadrant]

  const int c0 = tid, c1 = tid + 256;
  const int s0 = swz_col(c0), s1 = swz_col(c1);
  for (int kt = 0; kt < KT; ++kt) {
    const int k0 = kt * 32;
    // A tile [128,32]: chunk c -> row=c>>2, swizzled col
    GLD_LDS16(X + (size_t)(m0 + (c0 >> 2)) * 512 + k0 + s0, &As[wave * 512]);
    GLD_LDS16(X + (size_t)(m0 + (c1 >> 2)) * 512 + k0 + s1, &As[2048 + wave * 512]);
    // B tiles [4][32,32]: chunk c -> q=c>>7, row=(c>>2)&31, swizzled col
    GLD_LDS16(Wih + (size_t)((c0 >> 7) * 512 + n0 + ((c0 >> 2) & 31)) * 512 + k0 + s0,
              &Bs[wave * 512]);
    GLD_LDS16(Wih + (size_t)((c1 >> 7) * 512 + n0 + ((c1 >> 2) & 31)) * 512 + k0 + s1,
              &Bs[2048 + wave * 512]);
    asm volatile("s_waitcnt vmcnt(0)" ::: "memory");
    __syncthreads();
    const int fr = lane & 15, q = lane >> 4;
    const int koff = (q ^ ((fr >> 1) & 3)) * 8;  // matches staging swizzle
    bf16x8 a[4], b[4];
#pragma unroll
    for (int i = 0; i < 4; ++i) a[i] = *(const bf16x8*)&As[(wr + i * 16 + fr) * 32 + koff];
#pragma unroll
    for (int qd = 0; qd < 4; ++qd)
      b[qd] = *(const bf16x8*)&Bs[qd * 1024 + (wc + fr) * 32 + koff];
#pragma unroll
    for (int i = 0; i < 4; ++i)
#pragma unroll
      for (int qd = 0; qd < 4; ++qd)
        acc[i][qd] = __builtin_amdgcn_mfma_f32_16x16x32_bf16(a[i], b[qd], acc[i][qd], 0, 0, 0);
    __syncthreads();
  }
  const int rbase = (lane >> 4) * 4, cn = lane & 15;
  const int gn = n0 + wc + cn;  // column in [0,512)
  const float hv_i = hvec[gn];
  const float hv_f = hvec[gn + 512];
  const float hv_g = hvec[gn + 1024];
  const float hv_o = hvec[gn + 1536];
  const float cprev = cell[gn];
#pragma unroll
  for (int i = 0; i < 4; ++i)
#pragma unroll
    for (int r = 0; r < 4; ++r) {
      const int gm = m0 + wr + i * 16 + rbase + r;
      float si = sigmoid_fast(acc[i][0][r] + hv_i);
      float sf = sigmoid_fast(acc[i][1][r] + hv_f);
      float tg = tanh_fast(acc[i][2][r] + hv_g);
      float so = sigmoid_fast(acc[i][3][r] + hv_o);
      float cnew = sf * cprev + si * tg;
      float hnew = so * tanh_fast(cnew);
      H[(size_t)gm * 512 + gn] = f2bf(hnew);
      if (gm == 32767) { hlast[gn] = hnew; clast[gn] = cnew; }
    }
}

// ---------- GEMM3: Q = H @ W2^T + b2 (W2 fully LDS-resident) ----------
__global__ __launch_bounds__(256, 2) void gemm3(
    const unsigned short* __restrict__ H,    // [32768,512] bf16
    const unsigned short* __restrict__ W2b,  // [32,512] bf16
    const float* __restrict__ b2,            // [32]
    float* __restrict__ Q) {                 // [32768,32] fp32
  constexpr int KT = 16, LDW = 520;          // padded stride for Ws
  __shared__ __align__(16) unsigned short As[128 * 32];
  __shared__ __align__(16) unsigned short Ws[32 * LDW];
  const int tid = threadIdx.x, wave = tid >> 6, lane = tid & 63;
  const int m0 = blockIdx.x * 128;
  // preload W2: 2048 16B-chunks (not swizzled; not GLD-staged)
  for (int c = tid; c < 2048; c += 256) {
    const int row = c >> 6, col8 = c & 63;
    uint4 v = *(const uint4*)(W2b + row * 512 + col8 * 8);
    *(uint4*)&Ws[row * LDW + col8 * 8] = v;
  }
  f32x4 acc[2][2] = {};
  const int c0 = tid, c1 = tid + 256;
  const int s0 = swz_col(c0), s1 = swz_col(c1);
  for (int kt = 0; kt < KT; ++kt) {
    const int k0 = kt * 32;
    GLD_LDS16(H + (size_t)(m0 + (c0 >> 2)) * 512 + k0 + s0, &As[wave * 512]);
    GLD_LDS16(H + (size_t)(m0 + (c1 >> 2)) * 512 + k0 + s1, &As[2048 + wave * 512]);
    asm volatile("s_waitcnt vmcnt(0)" ::: "memory");
    __syncthreads();
    const int fr = lane & 15, q = lane >> 4, kq = q * 8;
    const int koff = (q ^ ((fr >> 1) & 3)) * 8;  // swizzled (As only)
    bf16x8 a[2], b[2];
#pragma unroll
    for (int i = 0; i < 2; ++i)
      a[i] = *(const bf16x8*)&As[(wave * 32 + i * 16 + fr) * 32 + koff];
#pragma unroll
    for (int j = 0; j < 2; ++j)
      b[j] = *(const bf16x8*)&Ws[(j * 16 + fr) * LDW + k0 + kq];
#pragma unroll
    for (int i = 0; i < 2; ++i)
#pragma unroll
      for (int j = 0; j < 2; ++j)
        acc[i][j] = __builtin_amdgcn_mfma_f32_16x16x32_bf16(a[i], b[j], acc[i][j], 0, 0, 0);
    __syncthreads();
  }
  const int rbase = (lane >> 4) * 4, cn = lane & 15;
#pragma unroll
  for (int i = 0; i < 2; ++i)
#pragma unroll
    for (int j = 0; j < 2; ++j) {
      const int gn = j * 16 + cn;
      const float bias = b2[gn];
#pragma unroll
      for (int r = 0; r < 4; ++r) {
        const int gm = m0 + wave * 32 + i * 16 + rbase + r;
        Q[(size_t)gm * 32 + gn] = acc[i][j][r] + bias;
      }
    }
}

// ---------- launch ----------
extern "C" void kernel_launch(void* const* d_in, const int* in_sizes, int n_in,
                              void* d_out, int out_size, void* d_ws, size_t ws_size,
                              hipStream_t stream) {
  const float* obs  = (const float*)d_in[0];
  const float* act  = (const float*)d_in[1];
  const float* hid  = (const float*)d_in[2];
  const float* cell = (const float*)d_in[3];
  const float* W1   = (const float*)d_in[4];
  const float* b1   = (const float*)d_in[5];
  const float* Wih  = (const float*)d_in[6];
  const float* bih  = (const float*)d_in[7];
  const float* Whh  = (const float*)d_in[8];
  const float* bhh  = (const float*)d_in[9];
  const float* W2   = (const float*)d_in[10];
  const float* b2   = (const float*)d_in[11];
  float* out = (float*)d_out;

  char* ws = (char*)d_ws;
  unsigned short* A0   = (unsigned short*)(ws);              // [B,544] bf16
  unsigned short* H    = (unsigned short*)(ws);              // alias A0 (dead after gemm1)
  unsigned short* X    = (unsigned short*)(ws + 35651584);   // [B,512] bf16
  unsigned short* W1b  = (unsigned short*)(ws + 69206016);
  unsigned short* Wihb = (unsigned short*)(ws + 69763072);
  unsigned short* W2b  = (unsigned short*)(ws + 71860224);
  float*          hvec = (float*)(ws + 71892992);

  prep_input<<<2176, 256, 0, stream>>>(obs, act, A0);
  cvt_bf16<<<272, 256, 0, stream>>>(W1, W1b, 512 * 544 / 4);
  cvt_bf16<<<1024, 256, 0, stream>>>(Wih, Wihb, 2048 * 512 / 4);
  cvt_bf16<<<16, 256, 0, stream>>>(W2, W2b, 32 * 512 / 4);
  calc_hvec<<<512, 256, 0, stream>>>(Whh, hid, bhh, bih, hvec);

  gemm1_relu<<<dim3(256, 4), 256, 0, stream>>>(A0, W1b, b1, X);
  gemm2_lstm<<<dim3(256, 16), 256, 0, stream>>>(X, Wihb, hvec, cell, H,
                                                out + 32768 * 32,
                                                out + 32768 * 32 + 512);
  gemm3<<<256, 256, 0, stream>>>(H, W2b, b2, out);
}

// Round 4
// 262.265 us; speedup vs baseline: 1.0668x; 1.0668x over previous
//
#include <hip/hip_runtime.h>
#include <stdint.h>

#define DEVINL __device__ __forceinline__

typedef __attribute__((ext_vector_type(8))) __bf16 bf16x8;
typedef __attribute__((ext_vector_type(4))) float f32x4;

// ---------- helpers ----------
DEVINL unsigned short f2bf(float f) {
  union { float f; unsigned int u; } v; v.f = f;
  unsigned int u = v.u;
  return (unsigned short)((u + 0x7fffu + ((u >> 16) & 1u)) >> 16);  // RNE
}

// v_rcp_f32-based activations (~1 ulp; output is bf16-rounded anyway).
DEVINL float sigm(float x) { return __builtin_amdgcn_rcpf(1.f + __expf(-x)); }
// tanh = 1 - 2/(1+e^{2x}); inf-safe both directions (x->+inf: rcp(inf)=0 -> 1;
// x->-inf: rcp(1)=1 -> -1). No clamp needed.
DEVINL float tanh_(float x) {
  return 1.f - 2.f * __builtin_amdgcn_rcpf(1.f + __expf(2.f * x));
}

// async global->LDS 16B per lane; lds base wave-uniform, HW scatters lane i to base+i*16
#define GLD_LDS16(gptr, lptr)                                                  \
  __builtin_amdgcn_global_load_lds(                                            \
      (__attribute__((address_space(1))) void*)(gptr),                         \
      (__attribute__((address_space(3))) void*)(lptr), 16, 0, 0)

// Split barriers for the software pipeline:
// TOPBAR: my prefetch GLDs have landed in LDS; everyone past it may read the buffer.
// BOTBAR: my LDS reads are complete; does NOT drain vmcnt -> prefetch stays in flight.
#define TOPBAR asm volatile("s_waitcnt vmcnt(0) lgkmcnt(0)\n\ts_barrier" ::: "memory")
#define BOTBAR asm volatile("s_waitcnt lgkmcnt(0)\n\ts_barrier" ::: "memory")

// XOR swizzle: LDS chunk (row, q') holds global chunk q' ^ ((row>>1)&3) of that row.
// For staging chunk index c (row=c>>2): source column-chunk = (c&3)^((c>>3)&3).
DEVINL int swz_col(int c) { return ((c & 3) ^ ((c >> 3) & 3)) * 8; }

// ---------- prep: concat(obs, act) -> bf16 [B,544] ----------
__global__ void prep_input(const float* __restrict__ obs,
                           const float* __restrict__ act,
                           unsigned short* __restrict__ A0) {
  const int total = 32768 * 68;  // 16B chunks (8 bf16) per row: 68
  for (int c = blockIdx.x * blockDim.x + threadIdx.x; c < total;
       c += gridDim.x * blockDim.x) {
    const int b = c / 68, c8 = c % 68;
    const float* src = (c8 < 64) ? (obs + (size_t)b * 512 + c8 * 8)
                                 : (act + (size_t)b * 32 + (c8 - 64) * 8);
    float4 f0 = *(const float4*)src;
    float4 f1 = *(const float4*)(src + 4);
    unsigned short u[8] = {f2bf(f0.x), f2bf(f0.y), f2bf(f0.z), f2bf(f0.w),
                           f2bf(f1.x), f2bf(f1.y), f2bf(f1.z), f2bf(f1.w)};
    *(uint4*)(A0 + (size_t)b * 544 + c8 * 8) = *(uint4*)u;
  }
}

// ---------- prep: fp32 -> bf16 generic ----------
__global__ void cvt_bf16(const float* __restrict__ src,
                         unsigned short* __restrict__ dst, int n4) {
  for (int i = blockIdx.x * blockDim.x + threadIdx.x; i < n4;
       i += gridDim.x * blockDim.x) {
    float4 f = *(const float4*)(src + (size_t)i * 4);
    unsigned short u[4] = {f2bf(f.x), f2bf(f.y), f2bf(f.z), f2bf(f.w)};
    *(uint2*)(dst + (size_t)i * 4) = *(uint2*)u;
  }
}

// ---------- prep: hvec[j] = dot(W_hh[j,:], hid) + b_hh[j] + b_ih[j] ----------
__global__ void calc_hvec(const float* __restrict__ Whh,
                          const float* __restrict__ hid,
                          const float* __restrict__ bhh,
                          const float* __restrict__ bih,
                          float* __restrict__ hvec) {
  const int j = blockIdx.x * 4 + (threadIdx.x >> 6);
  const int lane = threadIdx.x & 63;
  const float* w = Whh + (size_t)j * 512;
  float s = 0.f;
  for (int k = lane; k < 512; k += 64) s += w[k] * hid[k];
  for (int off = 32; off; off >>= 1) s += __shfl_down(s, off, 64);
  if (lane == 0) hvec[j] = s + bhh[j] + bih[j];
}

// ---------- GEMM1: X = relu(A0 @ W1^T + b1), bf16 out ----------
// Double-buffered pipeline + XCD swizzle (same m-tile's 4 n-blocks contiguous per XCD).
__global__ __launch_bounds__(256, 2) void gemm1_relu(
    const unsigned short* __restrict__ A0,   // [32768,544] bf16
    const unsigned short* __restrict__ W1b,  // [512,544] bf16
    const float* __restrict__ b1,            // [512]
    unsigned short* __restrict__ X) {        // [32768,512] bf16
  constexpr int KT = 17, LD = 544;
  __shared__ __align__(16) unsigned short As[2][128 * 32];
  __shared__ __align__(16) unsigned short Bs[2][128 * 32];
  const int tid = threadIdx.x, wave = tid >> 6, lane = tid & 63;
  // XCD swizzle: id -> (xcd, slot); same-xcd consecutive slots share m-tile.
  const int id = blockIdx.x, xcd = id & 7, slot = id >> 3;  // 1024 blocks
  const int m0 = (xcd * 32 + (slot >> 2)) * 128;            // 256 m-tiles
  const int n0 = (slot & 3) * 128;                          // 4 n-tiles
  const int wr = (wave >> 1) * 64, wc = (wave & 1) * 64;
  f32x4 acc[4][4] = {};

  const int c0 = tid, c1 = tid + 256;  // chunk: row=c>>2, swizzled col
  const unsigned short* pA0 = A0 + (size_t)(m0 + (c0 >> 2)) * LD + swz_col(c0);
  const unsigned short* pA1 = A0 + (size_t)(m0 + (c1 >> 2)) * LD + swz_col(c1);
  const unsigned short* pB0 = W1b + (size_t)(n0 + (c0 >> 2)) * LD + swz_col(c0);
  const unsigned short* pB1 = W1b + (size_t)(n0 + (c1 >> 2)) * LD + swz_col(c1);
  const int fr = lane & 15, q = lane >> 4;
  const int koff = (q ^ ((fr >> 1) & 3)) * 8;  // matches staging swizzle

#define STAGE1(buf)                                                            \
  do {                                                                         \
    GLD_LDS16(pA0, &As[(buf)][wave * 512]);                                    \
    GLD_LDS16(pA1, &As[(buf)][2048 + wave * 512]);                             \
    GLD_LDS16(pB0, &Bs[(buf)][wave * 512]);                                    \
    GLD_LDS16(pB1, &Bs[(buf)][2048 + wave * 512]);                             \
    pA0 += 32; pA1 += 32; pB0 += 32; pB1 += 32;                                \
  } while (0)

  STAGE1(0);
  for (int kt = 0; kt < KT; ++kt) {
    TOPBAR;                           // buf[kt&1] staged & visible
    if (kt + 1 < KT) STAGE1((kt + 1) & 1);  // prefetch stays in flight past BOTBAR
    const unsigned short* as = As[kt & 1];
    const unsigned short* bs = Bs[kt & 1];
    bf16x8 a[4], b[4];
#pragma unroll
    for (int i = 0; i < 4; ++i) a[i] = *(const bf16x8*)&as[(wr + i * 16 + fr) * 32 + koff];
#pragma unroll
    for (int j = 0; j < 4; ++j) b[j] = *(const bf16x8*)&bs[(wc + j * 16 + fr) * 32 + koff];
#pragma unroll
    for (int i = 0; i < 4; ++i)
#pragma unroll
      for (int j = 0; j < 4; ++j)
        acc[i][j] = __builtin_amdgcn_mfma_f32_16x16x32_bf16(a[i], b[j], acc[i][j], 0, 0, 0);
    BOTBAR;                           // LDS reads done; vmcnt NOT drained
  }
#undef STAGE1
  const int rbase = q * 4, cn = fr;
#pragma unroll
  for (int i = 0; i < 4; ++i)
#pragma unroll
    for (int j = 0; j < 4; ++j) {
      const int gn = n0 + wc + j * 16 + cn;
      const float bias = b1[gn];
#pragma unroll
      for (int r = 0; r < 4; ++r) {
        const int gm = m0 + wr + i * 16 + rbase + r;
        float v = acc[i][j][r] + bias;
        v = v > 0.f ? v : 0.f;
        X[(size_t)gm * 512 + gn] = f2bf(v);
      }
    }
}

// ---------- GEMM2 (4 gate quadrants) + LSTM epilogue ----------
__global__ __launch_bounds__(256, 2) void gemm2_lstm(
    const unsigned short* __restrict__ X,    // [32768,512] bf16
    const unsigned short* __restrict__ Wih,  // [2048,512] bf16
    const float* __restrict__ hvec,          // [2048]
    const float* __restrict__ cell,          // [512]
    unsigned short* __restrict__ H,          // [32768,512] bf16 out
    float* __restrict__ hlast,               // [512] fp32 out
    float* __restrict__ clast) {             // [512] fp32 out
  constexpr int KT = 16;
  __shared__ __align__(16) unsigned short As[2][128 * 32];
  __shared__ __align__(16) unsigned short Bs[2][4 * 32 * 32];
  const int tid = threadIdx.x, wave = tid >> 6, lane = tid & 63;
  // XCD swizzle: 16 n-blocks of one m-tile run consecutively on one XCD ->
  // the 128-row X slab (128 KB) stays in that XCD's 4 MiB L2.
  const int id = blockIdx.x, xcd = id & 7, slot = id >> 3;  // 4096 blocks
  const int m0 = (xcd * 32 + (slot >> 4)) * 128;            // 256 m-tiles
  const int n0 = (slot & 15) * 32;                          // 16 quadrant-col tiles
  const int wr = (wave >> 1) * 64, wc = (wave & 1) * 16;
  f32x4 acc[4][4] = {};                      // [row-tile][quadrant]

  const int c0 = tid, c1 = tid + 256;
  const unsigned short* pA0 = X + (size_t)(m0 + (c0 >> 2)) * 512 + swz_col(c0);
  const unsigned short* pA1 = X + (size_t)(m0 + (c1 >> 2)) * 512 + swz_col(c1);
  const unsigned short* pB0 =
      Wih + (size_t)((c0 >> 7) * 512 + n0 + ((c0 >> 2) & 31)) * 512 + swz_col(c0);
  const unsigned short* pB1 =
      Wih + (size_t)((c1 >> 7) * 512 + n0 + ((c1 >> 2) & 31)) * 512 + swz_col(c1);
  const int fr = lane & 15, q = lane >> 4;
  const int koff = (q ^ ((fr >> 1) & 3)) * 8;

#define STAGE2(buf)                                                            \
  do {                                                                         \
    GLD_LDS16(pA0, &As[(buf)][wave * 512]);                                    \
    GLD_LDS16(pA1, &As[(buf)][2048 + wave * 512]);                             \
    GLD_LDS16(pB0, &Bs[(buf)][wave * 512]);                                    \
    GLD_LDS16(pB1, &Bs[(buf)][2048 + wave * 512]);                             \
    pA0 += 32; pA1 += 32; pB0 += 32; pB1 += 32;                                \
  } while (0)

  STAGE2(0);
  for (int kt = 0; kt < KT; ++kt) {
    TOPBAR;
    if (kt + 1 < KT) STAGE2((kt + 1) & 1);
    const unsigned short* as = As[kt & 1];
    const unsigned short* bs = Bs[kt & 1];
    bf16x8 a[4], b[4];
#pragma unroll
    for (int i = 0; i < 4; ++i) a[i] = *(const bf16x8*)&as[(wr + i * 16 + fr) * 32 + koff];
#pragma unroll
    for (int qd = 0; qd < 4; ++qd)
      b[qd] = *(const bf16x8*)&bs[qd * 1024 + (wc + fr) * 32 + koff];
#pragma unroll
    for (int i = 0; i < 4; ++i)
#pragma unroll
      for (int qd = 0; qd < 4; ++qd)
        acc[i][qd] = __builtin_amdgcn_mfma_f32_16x16x32_bf16(a[i], b[qd], acc[i][qd], 0, 0, 0);
    BOTBAR;
  }
#undef STAGE2
  const int rbase = q * 4, cn = fr;
  const int gn = n0 + wc + cn;  // column in [0,512)
  const float hv_i = hvec[gn];
  const float hv_f = hvec[gn + 512];
  const float hv_g = hvec[gn + 1024];
  const float hv_o = hvec[gn + 1536];
  const float cprev = cell[gn];
#pragma unroll
  for (int i = 0; i < 4; ++i)
#pragma unroll
    for (int r = 0; r < 4; ++r) {
      const int gm = m0 + wr + i * 16 + rbase + r;
      float si = sigm(acc[i][0][r] + hv_i);
      float sf = sigm(acc[i][1][r] + hv_f);
      float tg = tanh_(acc[i][2][r] + hv_g);
      float so = sigm(acc[i][3][r] + hv_o);
      float cnew = sf * cprev + si * tg;
      float hnew = so * tanh_(cnew);
      H[(size_t)gm * 512 + gn] = f2bf(hnew);
      if (gm == 32767) { hlast[gn] = hnew; clast[gn] = cnew; }
    }
}

// ---------- GEMM3: Q = H @ W2^T + b2 (W2 fully LDS-resident) ----------
__global__ __launch_bounds__(256, 2) void gemm3(
    const unsigned short* __restrict__ H,    // [32768,512] bf16
    const unsigned short* __restrict__ W2b,  // [32,512] bf16
    const float* __restrict__ b2,            // [32]
    float* __restrict__ Q) {                 // [32768,32] fp32
  constexpr int KT = 16, LDW = 520;
  __shared__ __align__(16) unsigned short As[2][128 * 32];
  __shared__ __align__(16) unsigned short Ws[32 * LDW];
  const int tid = threadIdx.x, wave = tid >> 6, lane = tid & 63;
  // Same m_tile -> XCD map as gemm2, so H slab is read from the L2 that wrote it.
  const int id = blockIdx.x;                                 // 256 blocks
  const int m0 = ((id & 7) * 32 + (id >> 3)) * 128;
  // preload W2: 2048 16B-chunks (not swizzled; plain LDS writes)
  for (int c = tid; c < 2048; c += 256) {
    const int row = c >> 6, col8 = c & 63;
    *(uint4*)&Ws[row * LDW + col8 * 8] = *(const uint4*)(W2b + row * 512 + col8 * 8);
  }
  f32x4 acc[2][2] = {};
  const int c0 = tid, c1 = tid + 256;
  const unsigned short* pA0 = H + (size_t)(m0 + (c0 >> 2)) * 512 + swz_col(c0);
  const unsigned short* pA1 = H + (size_t)(m0 + (c1 >> 2)) * 512 + swz_col(c1);
  const int fr = lane & 15, q = lane >> 4, kq = q * 8;
  const int koff = (q ^ ((fr >> 1) & 3)) * 8;

#define STAGE3(buf)                                                            \
  do {                                                                         \
    GLD_LDS16(pA0, &As[(buf)][wave * 512]);                                    \
    GLD_LDS16(pA1, &As[(buf)][2048 + wave * 512]);                             \
    pA0 += 32; pA1 += 32;                                                      \
  } while (0)

  STAGE3(0);
  for (int kt = 0; kt < KT; ++kt) {
    TOPBAR;  // also orders the Ws preload (lgkmcnt(0) + barrier) before first read
    if (kt + 1 < KT) STAGE3((kt + 1) & 1);
    const unsigned short* as = As[kt & 1];
    const int k0 = kt * 32;
    bf16x8 a[2], b[2];
#pragma unroll
    for (int i = 0; i < 2; ++i)
      a[i] = *(const bf16x8*)&as[(wave * 32 + i * 16 + fr) * 32 + koff];
#pragma unroll
    for (int j = 0; j < 2; ++j)
      b[j] = *(const bf16x8*)&Ws[(j * 16 + fr) * LDW + k0 + kq];
#pragma unroll
    for (int i = 0; i < 2; ++i)
#pragma unroll
      for (int j = 0; j < 2; ++j)
        acc[i][j] = __builtin_amdgcn_mfma_f32_16x16x32_bf16(a[i], b[j], acc[i][j], 0, 0, 0);
    BOTBAR;
  }
#undef STAGE3
  const int rbase = q * 4, cn = fr;
#pragma unroll
  for (int i = 0; i < 2; ++i)
#pragma unroll
    for (int j = 0; j < 2; ++j) {
      const int gn = j * 16 + cn;
      const float bias = b2[gn];
#pragma unroll
      for (int r = 0; r < 4; ++r) {
        const int gm = m0 + wave * 32 + i * 16 + rbase + r;
        Q[(size_t)gm * 32 + gn] = acc[i][j][r] + bias;
      }
    }
}

// ---------- launch ----------
extern "C" void kernel_launch(void* const* d_in, const int* in_sizes, int n_in,
                              void* d_out, int out_size, void* d_ws, size_t ws_size,
                              hipStream_t stream) {
  const float* obs  = (const float*)d_in[0];
  const float* act  = (const float*)d_in[1];
  const float* hid  = (const float*)d_in[2];
  const float* cell = (const float*)d_in[3];
  const float* W1   = (const float*)d_in[4];
  const float* b1   = (const float*)d_in[5];
  const float* Wih  = (const float*)d_in[6];
  const float* bih  = (const float*)d_in[7];
  const float* Whh  = (const float*)d_in[8];
  const float* bhh  = (const float*)d_in[9];
  const float* W2   = (const float*)d_in[10];
  const float* b2   = (const float*)d_in[11];
  float* out = (float*)d_out;

  char* ws = (char*)d_ws;
  unsigned short* A0   = (unsigned short*)(ws);              // [B,544] bf16
  unsigned short* H    = (unsigned short*)(ws);              // alias A0 (dead after gemm1)
  unsigned short* X    = (unsigned short*)(ws + 35651584);   // [B,512] bf16
  unsigned short* W1b  = (unsigned short*)(ws + 69206016);
  unsigned short* Wihb = (unsigned short*)(ws + 69763072);
  unsigned short* W2b  = (unsigned short*)(ws + 71860224);
  float*          hvec = (float*)(ws + 71892992);

  prep_input<<<2176, 256, 0, stream>>>(obs, act, A0);
  cvt_bf16<<<272, 256, 0, stream>>>(W1, W1b, 512 * 544 / 4);
  cvt_bf16<<<1024, 256, 0, stream>>>(Wih, Wihb, 2048 * 512 / 4);
  cvt_bf16<<<16, 256, 0, stream>>>(W2, W2b, 32 * 512 / 4);
  calc_hvec<<<512, 256, 0, stream>>>(Whh, hid, bhh, bih, hvec);

  gemm1_relu<<<1024, 256, 0, stream>>>(A0, W1b, b1, X);
  gemm2_lstm<<<4096, 256, 0, stream>>>(X, Wihb, hvec, cell, H,
                                       out + 32768 * 32,
                                       out + 32768 * 32 + 512);
  gemm3<<<256, 256, 0, stream>>>(H, W2b, b2, out);
}

// Round 5
// 258.263 us; speedup vs baseline: 1.0833x; 1.0155x over previous
//
#include <hip/hip_runtime.h>
#include <stdint.h>

#define DEVINL __device__ __forceinline__

typedef __attribute__((ext_vector_type(8))) __bf16 bf16x8;
typedef __attribute__((ext_vector_type(4))) float f32x4;

// ---------- helpers ----------
DEVINL unsigned short f2bf(float f) {
  union { float f; unsigned int u; } v; v.f = f;
  unsigned int u = v.u;
  return (unsigned short)((u + 0x7fffu + ((u >> 16) & 1u)) >> 16);  // RNE
}

// v_rcp_f32-based activations (~1 ulp; output is bf16-rounded anyway).
DEVINL float sigm(float x) { return __builtin_amdgcn_rcpf(1.f + __expf(-x)); }
// tanh = 1 - 2/(1+e^{2x}); inf-safe both directions.
DEVINL float tanh_(float x) {
  return 1.f - 2.f * __builtin_amdgcn_rcpf(1.f + __expf(2.f * x));
}

// async global->LDS 16B per lane; lds base wave-uniform, HW scatters lane i to base+i*16
#define GLD_LDS16(gptr, lptr)                                                  \
  __builtin_amdgcn_global_load_lds(                                            \
      (__attribute__((address_space(1))) void*)(gptr),                         \
      (__attribute__((address_space(3))) void*)(lptr), 16, 0, 0)

// 3-stage pipeline barriers:
// TOPBAR_N: wait until only the NEXT stage's N loads remain in flight -> the
//           current stage has landed; next stage's prefetch stays in flight
//           across the barrier (the AITER "vmcnt never 0" pattern).
// TOPBAR_0: full drain (used for the last iteration only).
// BOTBAR:   my LDS reads done; vmcnt untouched.
#define TOPBAR_4 asm volatile("s_waitcnt vmcnt(4) lgkmcnt(0)\n\ts_barrier" ::: "memory")
#define TOPBAR_2 asm volatile("s_waitcnt vmcnt(2) lgkmcnt(0)\n\ts_barrier" ::: "memory")
#define TOPBAR_0 asm volatile("s_waitcnt vmcnt(0) lgkmcnt(0)\n\ts_barrier" ::: "memory")
#define BOTBAR   asm volatile("s_waitcnt lgkmcnt(0)\n\ts_barrier" ::: "memory")

// XOR swizzle: LDS chunk (row, q') holds global chunk q' ^ ((row>>1)&3) of that row.
DEVINL int swz_col(int c) { return ((c & 3) ^ ((c >> 3) & 3)) * 8; }

// ---------- prep: concat(obs, act) -> bf16 [B,544] ----------
__global__ void prep_input(const float* __restrict__ obs,
                           const float* __restrict__ act,
                           unsigned short* __restrict__ A0) {
  const int total = 32768 * 68;  // 16B chunks (8 bf16) per row: 68
  for (int c = blockIdx.x * blockDim.x + threadIdx.x; c < total;
       c += gridDim.x * blockDim.x) {
    const int b = c / 68, c8 = c % 68;
    const float* src = (c8 < 64) ? (obs + (size_t)b * 512 + c8 * 8)
                                 : (act + (size_t)b * 32 + (c8 - 64) * 8);
    float4 f0 = *(const float4*)src;
    float4 f1 = *(const float4*)(src + 4);
    unsigned short u[8] = {f2bf(f0.x), f2bf(f0.y), f2bf(f0.z), f2bf(f0.w),
                           f2bf(f1.x), f2bf(f1.y), f2bf(f1.z), f2bf(f1.w)};
    *(uint4*)(A0 + (size_t)b * 544 + c8 * 8) = *(uint4*)u;
  }
}

// ---------- prep: all three weight conversions in one launch ----------
__global__ void cvt_all(const float* __restrict__ W1, const float* __restrict__ Wih,
                        const float* __restrict__ W2,
                        unsigned short* __restrict__ W1b,
                        unsigned short* __restrict__ Wihb,
                        unsigned short* __restrict__ W2b) {
  const int i = blockIdx.x * blockDim.x + threadIdx.x;  // one float4 each
  const float* src; unsigned short* dst; int off;
  if (i < 69632) { src = W1; dst = W1b; off = i; }                          // 512*544/4
  else if (i < 69632 + 262144) { src = Wih; dst = Wihb; off = i - 69632; }  // 2048*512/4
  else if (i < 69632 + 262144 + 4096) { src = W2; dst = W2b; off = i - 331776; }
  else return;
  float4 f = *(const float4*)(src + (size_t)off * 4);
  unsigned short u[4] = {f2bf(f.x), f2bf(f.y), f2bf(f.z), f2bf(f.w)};
  *(uint2*)(dst + (size_t)off * 4) = *(uint2*)u;
}

// ---------- prep: hvec[j] = dot(W_hh[j,:], hid) + b_hh[j] + b_ih[j] ----------
__global__ void calc_hvec(const float* __restrict__ Whh,
                          const float* __restrict__ hid,
                          const float* __restrict__ bhh,
                          const float* __restrict__ bih,
                          float* __restrict__ hvec) {
  const int j = blockIdx.x * 4 + (threadIdx.x >> 6);
  const int lane = threadIdx.x & 63;
  const float* w = Whh + (size_t)j * 512;
  float s = 0.f;
  for (int k = lane; k < 512; k += 64) s += w[k] * hid[k];
  for (int off = 32; off; off >>= 1) s += __shfl_down(s, off, 64);
  if (lane == 0) hvec[j] = s + bhh[j] + bih[j];
}

// ---------- GEMM1: X = relu(A0 @ W1^T + b1), bf16 out ----------
// 3-stage pipeline + XCD swizzle.
__global__ __launch_bounds__(256, 2) void gemm1_relu(
    const unsigned short* __restrict__ A0,   // [32768,544] bf16
    const unsigned short* __restrict__ W1b,  // [512,544] bf16
    const float* __restrict__ b1,            // [512]
    unsigned short* __restrict__ X) {        // [32768,512] bf16
  constexpr int KT = 17, LD = 544;
  __shared__ __align__(16) unsigned short As[3 * 128 * 32];  // 24 KB
  __shared__ __align__(16) unsigned short Bs[3 * 128 * 32];  // 24 KB
  const int tid = threadIdx.x, wave = tid >> 6, lane = tid & 63;
  const int id = blockIdx.x, xcd = id & 7, slot = id >> 3;  // 1024 blocks
  const int m0 = (xcd * 32 + (slot >> 2)) * 128;            // 256 m-tiles
  const int n0 = (slot & 3) * 128;                          // 4 n-tiles
  const int wr = (wave >> 1) * 64, wc = (wave & 1) * 64;
  f32x4 acc[4][4] = {};

  const int c0 = tid, c1 = tid + 256;
  const unsigned short* pA0 = A0 + (size_t)(m0 + (c0 >> 2)) * LD + swz_col(c0);
  const unsigned short* pA1 = A0 + (size_t)(m0 + (c1 >> 2)) * LD + swz_col(c1);
  const unsigned short* pB0 = W1b + (size_t)(n0 + (c0 >> 2)) * LD + swz_col(c0);
  const unsigned short* pB1 = W1b + (size_t)(n0 + (c1 >> 2)) * LD + swz_col(c1);
  const int fr = lane & 15, q = lane >> 4;
  const int koff = (q ^ ((fr >> 1) & 3)) * 8;

#define STAGE1(buf)                                                            \
  do {                                                                         \
    GLD_LDS16(pA0, &As[(buf) * 4096 + wave * 512]);                            \
    GLD_LDS16(pA1, &As[(buf) * 4096 + 2048 + wave * 512]);                     \
    GLD_LDS16(pB0, &Bs[(buf) * 4096 + wave * 512]);                            \
    GLD_LDS16(pB1, &Bs[(buf) * 4096 + 2048 + wave * 512]);                     \
    pA0 += 32; pA1 += 32; pB0 += 32; pB1 += 32;                                \
  } while (0)

  STAGE1(0); STAGE1(1);
  int sbuf = 2, cbuf = 0;
  for (int kt = 0; kt < KT; ++kt) {
    if (kt + 1 < KT) TOPBAR_4; else TOPBAR_0;   // stage kt landed; kt+1 in flight
    if (kt + 2 < KT) { STAGE1(sbuf); sbuf = (sbuf == 2) ? 0 : sbuf + 1; }
    const unsigned short* as = &As[cbuf * 4096];
    const unsigned short* bs = &Bs[cbuf * 4096];
    cbuf = (cbuf == 2) ? 0 : cbuf + 1;
    bf16x8 a[4], b[4];
#pragma unroll
    for (int i = 0; i < 4; ++i) a[i] = *(const bf16x8*)&as[(wr + i * 16 + fr) * 32 + koff];
#pragma unroll
    for (int j = 0; j < 4; ++j) b[j] = *(const bf16x8*)&bs[(wc + j * 16 + fr) * 32 + koff];
#pragma unroll
    for (int i = 0; i < 4; ++i)
#pragma unroll
      for (int j = 0; j < 4; ++j)
        acc[i][j] = __builtin_amdgcn_mfma_f32_16x16x32_bf16(a[i], b[j], acc[i][j], 0, 0, 0);
    BOTBAR;
  }
#undef STAGE1
  const int rbase = q * 4, cn = fr;
#pragma unroll
  for (int i = 0; i < 4; ++i)
#pragma unroll
    for (int j = 0; j < 4; ++j) {
      const int gn = n0 + wc + j * 16 + cn;
      const float bias = b1[gn];
#pragma unroll
      for (int r = 0; r < 4; ++r) {
        const int gm = m0 + wr + i * 16 + rbase + r;
        float v = acc[i][j][r] + bias;
        v = v > 0.f ? v : 0.f;
        X[(size_t)gm * 512 + gn] = f2bf(v);
      }
    }
}

// ---------- GEMM2 (4 gate quadrants) + LSTM epilogue ----------
__global__ __launch_bounds__(256, 2) void gemm2_lstm(
    const unsigned short* __restrict__ X,    // [32768,512] bf16
    const unsigned short* __restrict__ Wih,  // [2048,512] bf16
    const float* __restrict__ hvec,          // [2048]
    const float* __restrict__ cell,          // [512]
    unsigned short* __restrict__ H,          // [32768,512] bf16 out
    float* __restrict__ hlast,               // [512] fp32 out
    float* __restrict__ clast) {             // [512] fp32 out
  constexpr int KT = 16;
  __shared__ __align__(16) unsigned short As[3 * 128 * 32];   // 24 KB
  __shared__ __align__(16) unsigned short Bs[3 * 4 * 32 * 32];// 24 KB
  const int tid = threadIdx.x, wave = tid >> 6, lane = tid & 63;
  // XCD swizzle: 16 n-blocks of one m-tile run consecutively on one XCD.
  const int id = blockIdx.x, xcd = id & 7, slot = id >> 3;  // 4096 blocks
  const int m0 = (xcd * 32 + (slot >> 4)) * 128;            // 256 m-tiles
  const int n0 = (slot & 15) * 32;                          // 16 quadrant-col tiles
  const int wr = (wave >> 1) * 64, wc = (wave & 1) * 16;
  f32x4 acc[4][4] = {};                      // [row-tile][quadrant]

  const int c0 = tid, c1 = tid + 256;
  const unsigned short* pA0 = X + (size_t)(m0 + (c0 >> 2)) * 512 + swz_col(c0);
  const unsigned short* pA1 = X + (size_t)(m0 + (c1 >> 2)) * 512 + swz_col(c1);
  const unsigned short* pB0 =
      Wih + (size_t)((c0 >> 7) * 512 + n0 + ((c0 >> 2) & 31)) * 512 + swz_col(c0);
  const unsigned short* pB1 =
      Wih + (size_t)((c1 >> 7) * 512 + n0 + ((c1 >> 2) & 31)) * 512 + swz_col(c1);
  const int fr = lane & 15, q = lane >> 4;
  const int koff = (q ^ ((fr >> 1) & 3)) * 8;

#define STAGE2(buf)                                                            \
  do {                                                                         \
    GLD_LDS16(pA0, &As[(buf) * 4096 + wave * 512]);                            \
    GLD_LDS16(pA1, &As[(buf) * 4096 + 2048 + wave * 512]);                     \
    GLD_LDS16(pB0, &Bs[(buf) * 4096 + wave * 512]);                            \
    GLD_LDS16(pB1, &Bs[(buf) * 4096 + 2048 + wave * 512]);                     \
    pA0 += 32; pA1 += 32; pB0 += 32; pB1 += 32;                                \
  } while (0)

  STAGE2(0); STAGE2(1);
  int sbuf = 2, cbuf = 0;
  for (int kt = 0; kt < KT; ++kt) {
    if (kt + 1 < KT) TOPBAR_4; else TOPBAR_0;
    if (kt + 2 < KT) { STAGE2(sbuf); sbuf = (sbuf == 2) ? 0 : sbuf + 1; }
    const unsigned short* as = &As[cbuf * 4096];
    const unsigned short* bs = &Bs[cbuf * 4096];
    cbuf = (cbuf == 2) ? 0 : cbuf + 1;
    bf16x8 a[4], b[4];
#pragma unroll
    for (int i = 0; i < 4; ++i) a[i] = *(const bf16x8*)&as[(wr + i * 16 + fr) * 32 + koff];
#pragma unroll
    for (int qd = 0; qd < 4; ++qd)
      b[qd] = *(const bf16x8*)&bs[qd * 1024 + (wc + fr) * 32 + koff];
#pragma unroll
    for (int i = 0; i < 4; ++i)
#pragma unroll
      for (int qd = 0; qd < 4; ++qd)
        acc[i][qd] = __builtin_amdgcn_mfma_f32_16x16x32_bf16(a[i], b[qd], acc[i][qd], 0, 0, 0);
    BOTBAR;
  }
#undef STAGE2
  const int rbase = q * 4, cn = fr;
  const int gn = n0 + wc + cn;  // column in [0,512)
  const float hv_i = hvec[gn];
  const float hv_f = hvec[gn + 512];
  const float hv_g = hvec[gn + 1024];
  const float hv_o = hvec[gn + 1536];
  const float cprev = cell[gn];
#pragma unroll
  for (int i = 0; i < 4; ++i)
#pragma unroll
    for (int r = 0; r < 4; ++r) {
      const int gm = m0 + wr + i * 16 + rbase + r;
      float si = sigm(acc[i][0][r] + hv_i);
      float sf = sigm(acc[i][1][r] + hv_f);
      float tg = tanh_(acc[i][2][r] + hv_g);
      float so = sigm(acc[i][3][r] + hv_o);
      float cnew = sf * cprev + si * tg;
      float hnew = so * tanh_(cnew);
      H[(size_t)gm * 512 + gn] = f2bf(hnew);
      if (gm == 32767) { hlast[gn] = hnew; clast[gn] = cnew; }
    }
}

// ---------- GEMM3: Q = H @ W2^T + b2 (W2 fully LDS-resident) ----------
__global__ __launch_bounds__(256, 2) void gemm3(
    const unsigned short* __restrict__ H,    // [32768,512] bf16
    const unsigned short* __restrict__ W2b,  // [32,512] bf16
    const float* __restrict__ b2,            // [32]
    float* __restrict__ Q) {                 // [32768,32] fp32
  constexpr int KT = 16, LDW = 520;
  __shared__ __align__(16) unsigned short As[3 * 128 * 32];  // 24 KB
  __shared__ __align__(16) unsigned short Ws[32 * LDW];      // 33.3 KB
  const int tid = threadIdx.x, wave = tid >> 6, lane = tid & 63;
  // Same m_tile -> XCD map as gemm2, so H slab is read from the L2 that wrote it.
  const int id = blockIdx.x;                                 // 256 blocks
  const int m0 = ((id & 7) * 32 + (id >> 3)) * 128;
  for (int c = tid; c < 2048; c += 256) {
    const int row = c >> 6, col8 = c & 63;
    *(uint4*)&Ws[row * LDW + col8 * 8] = *(const uint4*)(W2b + row * 512 + col8 * 8);
  }
  f32x4 acc[2][2] = {};
  const int c0 = tid, c1 = tid + 256;
  const unsigned short* pA0 = H + (size_t)(m0 + (c0 >> 2)) * 512 + swz_col(c0);
  const unsigned short* pA1 = H + (size_t)(m0 + (c1 >> 2)) * 512 + swz_col(c1);
  const int fr = lane & 15, q = lane >> 4, kq = q * 8;
  const int koff = (q ^ ((fr >> 1) & 3)) * 8;

#define STAGE3(buf)                                                            \
  do {                                                                         \
    GLD_LDS16(pA0, &As[(buf) * 4096 + wave * 512]);                            \
    GLD_LDS16(pA1, &As[(buf) * 4096 + 2048 + wave * 512]);                     \
    pA0 += 32; pA1 += 32;                                                      \
  } while (0)

  STAGE3(0); STAGE3(1);
  int sbuf = 2, cbuf = 0;
  for (int kt = 0; kt < KT; ++kt) {
    if (kt + 1 < KT) TOPBAR_2; else TOPBAR_0;  // first one also publishes Ws (lgkmcnt 0)
    if (kt + 2 < KT) { STAGE3(sbuf); sbuf = (sbuf == 2) ? 0 : sbuf + 1; }
    const unsigned short* as = &As[cbuf * 4096];
    cbuf = (cbuf == 2) ? 0 : cbuf + 1;
    const int k0 = kt * 32;
    bf16x8 a[2], b[2];
#pragma unroll
    for (int i = 0; i < 2; ++i)
      a[i] = *(const bf16x8*)&as[(wave * 32 + i * 16 + fr) * 32 + koff];
#pragma unroll
    for (int j = 0; j < 2; ++j)
      b[j] = *(const bf16x8*)&Ws[(j * 16 + fr) * LDW + k0 + kq];
#pragma unroll
    for (int i = 0; i < 2; ++i)
#pragma unroll
      for (int j = 0; j < 2; ++j)
        acc[i][j] = __builtin_amdgcn_mfma_f32_16x16x32_bf16(a[i], b[j], acc[i][j], 0, 0, 0);
    BOTBAR;
  }
#undef STAGE3
  const int rbase = q * 4, cn = fr;
#pragma unroll
  for (int i = 0; i < 2; ++i)
#pragma unroll
    for (int j = 0; j < 2; ++j) {
      const int gn = j * 16 + cn;
      const float bias = b2[gn];
#pragma unroll
      for (int r = 0; r < 4; ++r) {
        const int gm = m0 + wave * 32 + i * 16 + rbase + r;
        Q[(size_t)gm * 32 + gn] = acc[i][j][r] + bias;
      }
    }
}

// ---------- launch ----------
extern "C" void kernel_launch(void* const* d_in, const int* in_sizes, int n_in,
                              void* d_out, int out_size, void* d_ws, size_t ws_size,
                              hipStream_t stream) {
  const float* obs  = (const float*)d_in[0];
  const float* act  = (const float*)d_in[1];
  const float* hid  = (const float*)d_in[2];
  const float* cell = (const float*)d_in[3];
  const float* W1   = (const float*)d_in[4];
  const float* b1   = (const float*)d_in[5];
  const float* Wih  = (const float*)d_in[6];
  const float* bih  = (const float*)d_in[7];
  const float* Whh  = (const float*)d_in[8];
  const float* bhh  = (const float*)d_in[9];
  const float* W2   = (const float*)d_in[10];
  const float* b2   = (const float*)d_in[11];
  float* out = (float*)d_out;

  char* ws = (char*)d_ws;
  unsigned short* A0   = (unsigned short*)(ws);              // [B,544] bf16
  unsigned short* H    = (unsigned short*)(ws);              // alias A0 (dead after gemm1)
  unsigned short* X    = (unsigned short*)(ws + 35651584);   // [B,512] bf16
  unsigned short* W1b  = (unsigned short*)(ws + 69206016);
  unsigned short* Wihb = (unsigned short*)(ws + 69763072);
  unsigned short* W2b  = (unsigned short*)(ws + 71860224);
  float*          hvec = (float*)(ws + 71892992);

  prep_input<<<2176, 256, 0, stream>>>(obs, act, A0);
  cvt_all<<<1312, 256, 0, stream>>>(W1, Wih, W2, W1b, Wihb, W2b);
  calc_hvec<<<512, 256, 0, stream>>>(Whh, hid, bhh, bih, hvec);

  gemm1_relu<<<1024, 256, 0, stream>>>(A0, W1b, b1, X);
  gemm2_lstm<<<4096, 256, 0, stream>>>(X, Wihb, hvec, cell, H,
                                       out + 32768 * 32,
                                       out + 32768 * 32 + 512);
  gemm3<<<256, 256, 0, stream>>>(H, W2b, b2, out);
}

// Round 6
// 247.146 us; speedup vs baseline: 1.1321x; 1.0450x over previous
//
#include <hip/hip_runtime.h>
#include <stdint.h>

#define DEVINL __device__ __forceinline__

typedef __attribute__((ext_vector_type(8))) __bf16 bf16x8;
typedef __attribute__((ext_vector_type(4))) float f32x4;

// ---------- helpers ----------
DEVINL unsigned short f2bf(float f) {
  union { float f; unsigned int u; } v; v.f = f;
  unsigned int u = v.u;
  return (unsigned short)((u + 0x7fffu + ((u >> 16) & 1u)) >> 16);  // RNE
}

// v_rcp_f32-based activations (~1 ulp; output is bf16-rounded anyway).
DEVINL float sigm(float x) { return __builtin_amdgcn_rcpf(1.f + __expf(-x)); }
// tanh = 1 - 2/(1+e^{2x}); inf-safe both directions.
DEVINL float tanh_(float x) {
  return 1.f - 2.f * __builtin_amdgcn_rcpf(1.f + __expf(2.f * x));
}

// async global->LDS 16B per lane; lds base wave-uniform, HW scatters lane i to base+i*16
#define GLD_LDS16(gptr, lptr)                                                  \
  __builtin_amdgcn_global_load_lds(                                            \
      (__attribute__((address_space(1))) void*)(gptr),                         \
      (__attribute__((address_space(3))) void*)(lptr), 16, 0, 0)

// 2-buffer pipeline, stage-before-barrier:
// STAGE(k+1) is issued BEFORE the top barrier; TOPBAR_N waits vmcnt(N) where
// N = loads of one stage -> stage k has landed, stage k+1 crosses the barrier
// in flight (AITER "vmcnt never 0" pattern). Last iter peels to vmcnt(0).
#define TOPBAR_4 asm volatile("s_waitcnt vmcnt(4) lgkmcnt(0)\n\ts_barrier" ::: "memory")
#define TOPBAR_1 asm volatile("s_waitcnt vmcnt(1) lgkmcnt(0)\n\ts_barrier" ::: "memory")
#define TOPBAR_0 asm volatile("s_waitcnt vmcnt(0) lgkmcnt(0)\n\ts_barrier" ::: "memory")
#define BOTBAR   asm volatile("s_waitcnt lgkmcnt(0)\n\ts_barrier" ::: "memory")

// XOR swizzle: LDS chunk (row, q') holds global chunk q' ^ ((row>>1)&3) of that row.
DEVINL int swz_col(int c) { return ((c & 3) ^ ((c >> 3) & 3)) * 8; }

// ---------- fused prep: input concat + weight cvt + hvec, grid-sectioned ----------
__global__ void prep_all(const float* __restrict__ obs, const float* __restrict__ act,
                         const float* __restrict__ W1, const float* __restrict__ Wih,
                         const float* __restrict__ W2, const float* __restrict__ Whh,
                         const float* __restrict__ hid, const float* __restrict__ bhh,
                         const float* __restrict__ bih,
                         unsigned short* __restrict__ A0, unsigned short* __restrict__ W1b,
                         unsigned short* __restrict__ Wihb, unsigned short* __restrict__ W2b,
                         float* __restrict__ hvec) {
  const int bid = blockIdx.x, tid = threadIdx.x;
  if (bid < 2176) {
    // section A: concat(obs, act) -> bf16 [32768, 544]
    const int total = 32768 * 68;  // 16B chunks per row: 68
    for (int c = bid * 256 + tid; c < total; c += 2176 * 256) {
      const int b = c / 68, c8 = c % 68;
      const float* src = (c8 < 64) ? (obs + (size_t)b * 512 + c8 * 8)
                                   : (act + (size_t)b * 32 + (c8 - 64) * 8);
      float4 f0 = *(const float4*)src;
      float4 f1 = *(const float4*)(src + 4);
      unsigned short u[8] = {f2bf(f0.x), f2bf(f0.y), f2bf(f0.z), f2bf(f0.w),
                             f2bf(f1.x), f2bf(f1.y), f2bf(f1.z), f2bf(f1.w)};
      *(uint4*)(A0 + (size_t)b * 544 + c8 * 8) = *(uint4*)u;
    }
  } else if (bid < 2176 + 1312) {
    // section B: fp32 -> bf16 weight conversion (one float4 per thread)
    const int i = (bid - 2176) * 256 + tid;
    const float* src; unsigned short* dst; int off;
    if (i < 69632) { src = W1; dst = W1b; off = i; }                          // 512*544/4
    else if (i < 69632 + 262144) { src = Wih; dst = Wihb; off = i - 69632; }  // 2048*512/4
    else { src = W2; dst = W2b; off = i - 331776; }                           // 32*512/4
    float4 f = *(const float4*)(src + (size_t)off * 4);
    unsigned short u[4] = {f2bf(f.x), f2bf(f.y), f2bf(f.z), f2bf(f.w)};
    *(uint2*)(dst + (size_t)off * 4) = *(uint2*)u;
  } else {
    // section C: hvec[j] = dot(W_hh[j,:], hid) + b_hh[j] + b_ih[j]
    const int j = (bid - 3488) * 4 + (tid >> 6);
    const int lane = tid & 63;
    const float* w = Whh + (size_t)j * 512;
    float s = 0.f;
    for (int k = lane; k < 512; k += 64) s += w[k] * hid[k];
    for (int off = 32; off; off >>= 1) s += __shfl_down(s, off, 64);
    if (lane == 0) hvec[j] = s + bhh[j] + bih[j];
  }
}

// ---------- GEMM1: X = relu(A0 @ W1^T + b1), bf16 out ----------
__global__ __launch_bounds__(256, 2) void gemm1_relu(
    const unsigned short* __restrict__ A0,   // [32768,544] bf16
    const unsigned short* __restrict__ W1b,  // [512,544] bf16
    const float* __restrict__ b1,            // [512]
    unsigned short* __restrict__ X) {        // [32768,512] bf16
  constexpr int KT = 17, LD = 544;
  __shared__ __align__(16) unsigned short As[2][128 * 32];  // 16 KB
  __shared__ __align__(16) unsigned short Bs[2][128 * 32];  // 16 KB
  const int tid = threadIdx.x, wave = tid >> 6, lane = tid & 63;
  const int id = blockIdx.x, xcd = id & 7, slot = id >> 3;  // 1024 blocks
  const int m0 = (xcd * 32 + (slot >> 2)) * 128;            // 256 m-tiles
  const int n0 = (slot & 3) * 128;                          // 4 n-tiles
  const int wr = (wave >> 1) * 64, wc = (wave & 1) * 64;
  f32x4 acc[4][4] = {};

  const int c0 = tid, c1 = tid + 256;
  const unsigned short* pA0 = A0 + (size_t)(m0 + (c0 >> 2)) * LD + swz_col(c0);
  const unsigned short* pA1 = A0 + (size_t)(m0 + (c1 >> 2)) * LD + swz_col(c1);
  const unsigned short* pB0 = W1b + (size_t)(n0 + (c0 >> 2)) * LD + swz_col(c0);
  const unsigned short* pB1 = W1b + (size_t)(n0 + (c1 >> 2)) * LD + swz_col(c1);
  const int fr = lane & 15, q = lane >> 4;
  const int koff = (q ^ ((fr >> 1) & 3)) * 8;

#define STAGE1(buf)                                                            \
  do {                                                                         \
    GLD_LDS16(pA0, &As[(buf)][wave * 512]);                                    \
    GLD_LDS16(pA1, &As[(buf)][2048 + wave * 512]);                             \
    GLD_LDS16(pB0, &Bs[(buf)][wave * 512]);                                    \
    GLD_LDS16(pB1, &Bs[(buf)][2048 + wave * 512]);                             \
    pA0 += 32; pA1 += 32; pB0 += 32; pB1 += 32;                                \
  } while (0)

  STAGE1(0);
  for (int kt = 0; kt < KT; ++kt) {
    if (kt + 1 < KT) { STAGE1((kt + 1) & 1); TOPBAR_4; } else { TOPBAR_0; }
    const unsigned short* as = As[kt & 1];
    const unsigned short* bs = Bs[kt & 1];
    bf16x8 a[4], b[4];
#pragma unroll
    for (int i = 0; i < 4; ++i) a[i] = *(const bf16x8*)&as[(wr + i * 16 + fr) * 32 + koff];
#pragma unroll
    for (int j = 0; j < 4; ++j) b[j] = *(const bf16x8*)&bs[(wc + j * 16 + fr) * 32 + koff];
#pragma unroll
    for (int i = 0; i < 4; ++i)
#pragma unroll
      for (int j = 0; j < 4; ++j)
        acc[i][j] = __builtin_amdgcn_mfma_f32_16x16x32_bf16(a[i], b[j], acc[i][j], 0, 0, 0);
    BOTBAR;
  }
#undef STAGE1
  const int rbase = q * 4, cn = fr;
#pragma unroll
  for (int i = 0; i < 4; ++i)
#pragma unroll
    for (int j = 0; j < 4; ++j) {
      const int gn = n0 + wc + j * 16 + cn;
      const float bias = b1[gn];
#pragma unroll
      for (int r = 0; r < 4; ++r) {
        const int gm = m0 + wr + i * 16 + rbase + r;
        float v = acc[i][j][r] + bias;
        v = v > 0.f ? v : 0.f;
        X[(size_t)gm * 512 + gn] = f2bf(v);
      }
    }
}

// ---------- GEMM2 (4 gate quadrants) + LSTM epilogue ----------
__global__ __launch_bounds__(256, 2) void gemm2_lstm(
    const unsigned short* __restrict__ X,    // [32768,512] bf16
    const unsigned short* __restrict__ Wih,  // [2048,512] bf16
    const float* __restrict__ hvec,          // [2048]
    const float* __restrict__ cell,          // [512]
    unsigned short* __restrict__ H,          // [32768,512] bf16 out
    float* __restrict__ hlast,               // [512] fp32 out
    float* __restrict__ clast) {             // [512] fp32 out
  constexpr int KT = 16;
  __shared__ __align__(16) unsigned short As[2][128 * 32];    // 16 KB
  __shared__ __align__(16) unsigned short Bs[2][4 * 32 * 32]; // 16 KB
  const int tid = threadIdx.x, wave = tid >> 6, lane = tid & 63;
  // XCD swizzle: 16 n-blocks of one m-tile run consecutively on one XCD.
  const int id = blockIdx.x, xcd = id & 7, slot = id >> 3;  // 4096 blocks
  const int m0 = (xcd * 32 + (slot >> 4)) * 128;            // 256 m-tiles
  const int n0 = (slot & 15) * 32;                          // 16 quadrant-col tiles
  const int wr = (wave >> 1) * 64, wc = (wave & 1) * 16;
  f32x4 acc[4][4] = {};                      // [row-tile][quadrant]

  const int c0 = tid, c1 = tid + 256;
  const unsigned short* pA0 = X + (size_t)(m0 + (c0 >> 2)) * 512 + swz_col(c0);
  const unsigned short* pA1 = X + (size_t)(m0 + (c1 >> 2)) * 512 + swz_col(c1);
  const unsigned short* pB0 =
      Wih + (size_t)((c0 >> 7) * 512 + n0 + ((c0 >> 2) & 31)) * 512 + swz_col(c0);
  const unsigned short* pB1 =
      Wih + (size_t)((c1 >> 7) * 512 + n0 + ((c1 >> 2) & 31)) * 512 + swz_col(c1);
  const int fr = lane & 15, q = lane >> 4;
  const int koff = (q ^ ((fr >> 1) & 3)) * 8;

#define STAGE2(buf)                                                            \
  do {                                                                         \
    GLD_LDS16(pA0, &As[(buf)][wave * 512]);                                    \
    GLD_LDS16(pA1, &As[(buf)][2048 + wave * 512]);                             \
    GLD_LDS16(pB0, &Bs[(buf)][wave * 512]);                                    \
    GLD_LDS16(pB1, &Bs[(buf)][2048 + wave * 512]);                             \
    pA0 += 32; pA1 += 32; pB0 += 32; pB1 += 32;                                \
  } while (0)

  STAGE2(0);
  for (int kt = 0; kt < KT; ++kt) {
    if (kt + 1 < KT) { STAGE2((kt + 1) & 1); TOPBAR_4; } else { TOPBAR_0; }
    const unsigned short* as = As[kt & 1];
    const unsigned short* bs = Bs[kt & 1];
    bf16x8 a[4], b[4];
#pragma unroll
    for (int i = 0; i < 4; ++i) a[i] = *(const bf16x8*)&as[(wr + i * 16 + fr) * 32 + koff];
#pragma unroll
    for (int qd = 0; qd < 4; ++qd)
      b[qd] = *(const bf16x8*)&bs[qd * 1024 + (wc + fr) * 32 + koff];
#pragma unroll
    for (int i = 0; i < 4; ++i)
#pragma unroll
      for (int qd = 0; qd < 4; ++qd)
        acc[i][qd] = __builtin_amdgcn_mfma_f32_16x16x32_bf16(a[i], b[qd], acc[i][qd], 0, 0, 0);
    BOTBAR;
  }
#undef STAGE2
  const int rbase = q * 4, cn = fr;
  const int gn = n0 + wc + cn;  // column in [0,512)
  const float hv_i = hvec[gn];
  const float hv_f = hvec[gn + 512];
  const float hv_g = hvec[gn + 1024];
  const float hv_o = hvec[gn + 1536];
  const float cprev = cell[gn];
#pragma unroll
  for (int i = 0; i < 4; ++i)
#pragma unroll
    for (int r = 0; r < 4; ++r) {
      const int gm = m0 + wr + i * 16 + rbase + r;
      float si = sigm(acc[i][0][r] + hv_i);
      float sf = sigm(acc[i][1][r] + hv_f);
      float tg = tanh_(acc[i][2][r] + hv_g);
      float so = sigm(acc[i][3][r] + hv_o);
      float cnew = sf * cprev + si * tg;
      float hnew = so * tanh_(cnew);
      H[(size_t)gm * 512 + gn] = f2bf(hnew);
      if (gm == 32767) { hlast[gn] = hnew; clast[gn] = cnew; }
    }
}

// ---------- GEMM3: Q = H @ W2^T + b2 (64-row tiles, 512 blocks) ----------
__global__ __launch_bounds__(256, 2) void gemm3(
    const unsigned short* __restrict__ H,    // [32768,512] bf16
    const unsigned short* __restrict__ W2b,  // [32,512] bf16
    const float* __restrict__ b2,            // [32]
    float* __restrict__ Q) {                 // [32768,32] fp32
  constexpr int KT = 16, LDW = 520;
  __shared__ __align__(16) unsigned short As[2][64 * 32];    // 8 KB
  __shared__ __align__(16) unsigned short Ws[32 * LDW];      // 32.5 KB
  const int tid = threadIdx.x, wave = tid >> 6, lane = tid & 63;
  // Same m-tile -> XCD map as gemm2 (parent 128-tile index >> 5 = xcd).
  const int id = blockIdx.x;                                 // 512 blocks
  const int m0 = ((id & 7) * 64 + (id >> 3)) * 64;           // 64-row tiles
  for (int c = tid; c < 2048; c += 256) {
    const int row = c >> 6, col8 = c & 63;
    *(uint4*)&Ws[row * LDW + col8 * 8] = *(const uint4*)(W2b + row * 512 + col8 * 8);
  }
  f32x4 acc[2] = {};
  const int c0 = tid;  // 256 chunks = 64 rows x 4, one per thread
  const unsigned short* pA0 = H + (size_t)(m0 + (c0 >> 2)) * 512 + swz_col(c0);
  const int fr = lane & 15, q = lane >> 4;
  const int koff = (q ^ ((fr >> 1) & 3)) * 8;

#define STAGE3(buf)                                                            \
  do {                                                                         \
    GLD_LDS16(pA0, &As[(buf)][wave * 512]);                                    \
    pA0 += 32;                                                                 \
  } while (0)

  STAGE3(0);
  for (int kt = 0; kt < KT; ++kt) {
    if (kt + 1 < KT) { STAGE3((kt + 1) & 1); TOPBAR_1; } else { TOPBAR_0; }
    const unsigned short* as = As[kt & 1];
    const int k0 = kt * 32;
    // wave covers rows wave*16 .. wave*16+15
    bf16x8 a  = *(const bf16x8*)&as[(wave * 16 + fr) * 32 + koff];
    bf16x8 b0 = *(const bf16x8*)&Ws[fr * LDW + k0 + q * 8];
    bf16x8 b1 = *(const bf16x8*)&Ws[(16 + fr) * LDW + k0 + q * 8];
    acc[0] = __builtin_amdgcn_mfma_f32_16x16x32_bf16(a, b0, acc[0], 0, 0, 0);
    acc[1] = __builtin_amdgcn_mfma_f32_16x16x32_bf16(a, b1, acc[1], 0, 0, 0);
    BOTBAR;
  }
#undef STAGE3
  const int rbase = q * 4;
#pragma unroll
  for (int j = 0; j < 2; ++j) {
    const int gn = j * 16 + fr;
    const float bias = b2[gn];
#pragma unroll
    for (int r = 0; r < 4; ++r) {
      const int gm = m0 + wave * 16 + rbase + r;
      Q[(size_t)gm * 32 + gn] = acc[j][r] + bias;
    }
  }
}

// ---------- launch ----------
extern "C" void kernel_launch(void* const* d_in, const int* in_sizes, int n_in,
                              void* d_out, int out_size, void* d_ws, size_t ws_size,
                              hipStream_t stream) {
  const float* obs  = (const float*)d_in[0];
  const float* act  = (const float*)d_in[1];
  const float* hid  = (const float*)d_in[2];
  const float* cell = (const float*)d_in[3];
  const float* W1   = (const float*)d_in[4];
  const float* b1   = (const float*)d_in[5];
  const float* Wih  = (const float*)d_in[6];
  const float* bih  = (const float*)d_in[7];
  const float* Whh  = (const float*)d_in[8];
  const float* bhh  = (const float*)d_in[9];
  const float* W2   = (const float*)d_in[10];
  const float* b2   = (const float*)d_in[11];
  float* out = (float*)d_out;

  char* ws = (char*)d_ws;
  unsigned short* A0   = (unsigned short*)(ws);              // [B,544] bf16
  unsigned short* H    = (unsigned short*)(ws);              // alias A0 (dead after gemm1)
  unsigned short* X    = (unsigned short*)(ws + 35651584);   // [B,512] bf16
  unsigned short* W1b  = (unsigned short*)(ws + 69206016);
  unsigned short* Wihb = (unsigned short*)(ws + 69763072);
  unsigned short* W2b  = (unsigned short*)(ws + 71860224);
  float*          hvec = (float*)(ws + 71892992);

  prep_all<<<4000, 256, 0, stream>>>(obs, act, W1, Wih, W2, Whh, hid, bhh, bih,
                                     A0, W1b, Wihb, W2b, hvec);
  gemm1_relu<<<1024, 256, 0, stream>>>(A0, W1b, b1, X);
  gemm2_lstm<<<4096, 256, 0, stream>>>(X, Wihb, hvec, cell, H,
                                       out + 32768 * 32,
                                       out + 32768 * 32 + 512);
  gemm3<<<512, 256, 0, stream>>>(H, W2b, b2, out);
}

// Round 7
// 239.448 us; speedup vs baseline: 1.1685x; 1.0322x over previous
//
#include <hip/hip_runtime.h>
#include <stdint.h>

#define DEVINL __device__ __forceinline__

typedef __attribute__((ext_vector_type(8))) __bf16 bf16x8;
typedef __attribute__((ext_vector_type(4))) float f32x4;

// ---------- helpers ----------
DEVINL unsigned short f2bf(float f) {
  union { float f; unsigned int u; } v; v.f = f;
  unsigned int u = v.u;
  return (unsigned short)((u + 0x7fffu + ((u >> 16) & 1u)) >> 16);  // RNE
}

// float -> OCP e4m3 byte via HW cvt (gfx950 = OCP semantics)
DEVINL unsigned char f2fp8(float f) {
  return (unsigned char)(__builtin_amdgcn_cvt_pk_fp8_f32(f, f, 0, false) & 0xff);
}

// v_rcp_f32-based activations (~1 ulp; output is bf16-rounded anyway).
DEVINL float sigm(float x) { return __builtin_amdgcn_rcpf(1.f + __expf(-x)); }
// tanh = 1 - 2/(1+e^{2x}); inf-safe both directions.
DEVINL float tanh_(float x) {
  return 1.f - 2.f * __builtin_amdgcn_rcpf(1.f + __expf(2.f * x));
}

// async global->LDS 16B per lane; lds base wave-uniform, HW scatters lane i to base+i*16
#define GLD_LDS16(gptr, lptr)                                                  \
  __builtin_amdgcn_global_load_lds(                                            \
      (__attribute__((address_space(1))) void*)(gptr),                         \
      (__attribute__((address_space(3))) void*)(lptr), 16, 0, 0)

// Stage-before-barrier pipeline: STAGE(k+1) issued BEFORE the top barrier;
// TOPBAR_N waits vmcnt(N) = one stage's loads -> stage k landed, stage k+1
// crosses the barrier in flight. Last iter peels to vmcnt(0).
#define TOPBAR_4 asm volatile("s_waitcnt vmcnt(4) lgkmcnt(0)\n\ts_barrier" ::: "memory")
#define TOPBAR_2 asm volatile("s_waitcnt vmcnt(2) lgkmcnt(0)\n\ts_barrier" ::: "memory")
#define TOPBAR_1 asm volatile("s_waitcnt vmcnt(1) lgkmcnt(0)\n\ts_barrier" ::: "memory")
#define TOPBAR_0 asm volatile("s_waitcnt vmcnt(0) lgkmcnt(0)\n\ts_barrier" ::: "memory")
#define BOTBAR   asm volatile("s_waitcnt lgkmcnt(0)\n\ts_barrier" ::: "memory")

// bf16 XOR swizzle (16B chunks of 64B rows): source column-chunk for staging
// chunk c (row=c>>2) = (c&3)^((c>>3)&3).
DEVINL int swz_col(int c) { return ((c & 3) ^ ((c >> 3) & 3)) * 8; }
// fp8 swizzle (16B halves of 32B rows): swap halves when (row>>2)&1, row=c>>1.
DEVINL int swz8(int c) { return ((c & 1) ^ ((c >> 3) & 1)) * 16; }

// ---------- fused prep: input concat + weight cvt + hvec, grid-sectioned ----------
__global__ void prep_all(const float* __restrict__ obs, const float* __restrict__ act,
                         const float* __restrict__ W1, const float* __restrict__ Wih,
                         const float* __restrict__ W2, const float* __restrict__ Whh,
                         const float* __restrict__ hid, const float* __restrict__ bhh,
                         const float* __restrict__ bih,
                         unsigned short* __restrict__ A0, unsigned short* __restrict__ W1b,
                         unsigned char* __restrict__ Wih8, unsigned short* __restrict__ W2b,
                         float* __restrict__ hvec) {
  const int bid = blockIdx.x, tid = threadIdx.x;
  if (bid < 2176) {
    // section A: concat(obs, act) -> bf16 [32768, 544]
    const int total = 32768 * 68;
    for (int c = bid * 256 + tid; c < total; c += 2176 * 256) {
      const int b = c / 68, c8 = c % 68;
      const float* src = (c8 < 64) ? (obs + (size_t)b * 512 + c8 * 8)
                                   : (act + (size_t)b * 32 + (c8 - 64) * 8);
      float4 f0 = *(const float4*)src;
      float4 f1 = *(const float4*)(src + 4);
      unsigned short u[8] = {f2bf(f0.x), f2bf(f0.y), f2bf(f0.z), f2bf(f0.w),
                             f2bf(f1.x), f2bf(f1.y), f2bf(f1.z), f2bf(f1.w)};
      *(uint4*)(A0 + (size_t)b * 544 + c8 * 8) = *(uint4*)u;
    }
  } else if (bid < 2176 + 1312) {
    // section B: weight conversion (one float4 per thread)
    const int i = (bid - 2176) * 256 + tid;
    if (i < 69632) {                       // W1 -> bf16
      float4 f = *(const float4*)(W1 + (size_t)i * 4);
      unsigned short u[4] = {f2bf(f.x), f2bf(f.y), f2bf(f.z), f2bf(f.w)};
      *(uint2*)(W1b + (size_t)i * 4) = *(uint2*)u;
    } else if (i < 69632 + 262144) {       // Wih -> fp8 e4m3, scaled x16
      const int off = i - 69632;
      float4 f = *(const float4*)(Wih + (size_t)off * 4);
      int pk = __builtin_amdgcn_cvt_pk_fp8_f32(f.x * 16.f, f.y * 16.f, 0, false);
      pk = __builtin_amdgcn_cvt_pk_fp8_f32(f.z * 16.f, f.w * 16.f, pk, true);
      *(unsigned int*)(Wih8 + (size_t)off * 4) = (unsigned int)pk;
    } else {                               // W2 -> bf16
      const int off = i - 331776;
      float4 f = *(const float4*)(W2 + (size_t)off * 4);
      unsigned short u[4] = {f2bf(f.x), f2bf(f.y), f2bf(f.z), f2bf(f.w)};
      *(uint2*)(W2b + (size_t)off * 4) = *(uint2*)u;
    }
  } else {
    // section C: hvec[j] = dot(W_hh[j,:], hid) + b_hh[j] + b_ih[j]
    const int j = (bid - 3488) * 4 + (tid >> 6);
    const int lane = tid & 63;
    const float* w = Whh + (size_t)j * 512;
    float s = 0.f;
    for (int k = lane; k < 512; k += 64) s += w[k] * hid[k];
    for (int off = 32; off; off >>= 1) s += __shfl_down(s, off, 64);
    if (lane == 0) hvec[j] = s + bhh[j] + bih[j];
  }
}

// ---------- GEMM1: X8 = fp8(relu(A0 @ W1^T + b1) * 8) ----------
__global__ __launch_bounds__(256, 2) void gemm1_relu(
    const unsigned short* __restrict__ A0,   // [32768,544] bf16
    const unsigned short* __restrict__ W1b,  // [512,544] bf16
    const float* __restrict__ b1,            // [512]
    unsigned char* __restrict__ X8) {        // [32768,512] fp8 (x8 scale)
  constexpr int KT = 17, LD = 544;
  __shared__ __align__(16) unsigned short As[2][128 * 32];  // 16 KB
  __shared__ __align__(16) unsigned short Bs[2][128 * 32];  // 16 KB
  const int tid = threadIdx.x, wave = tid >> 6, lane = tid & 63;
  const int id = blockIdx.x, xcd = id & 7, slot = id >> 3;  // 1024 blocks
  const int m0 = (xcd * 32 + (slot >> 2)) * 128;            // 256 m-tiles
  const int n0 = (slot & 3) * 128;                          // 4 n-tiles
  const int wr = (wave >> 1) * 64, wc = (wave & 1) * 64;
  f32x4 acc[4][4] = {};

  const int c0 = tid, c1 = tid + 256;
  const unsigned short* pA0 = A0 + (size_t)(m0 + (c0 >> 2)) * LD + swz_col(c0);
  const unsigned short* pA1 = A0 + (size_t)(m0 + (c1 >> 2)) * LD + swz_col(c1);
  const unsigned short* pB0 = W1b + (size_t)(n0 + (c0 >> 2)) * LD + swz_col(c0);
  const unsigned short* pB1 = W1b + (size_t)(n0 + (c1 >> 2)) * LD + swz_col(c1);
  const int fr = lane & 15, q = lane >> 4;
  const int koff = (q ^ ((fr >> 1) & 3)) * 8;

#define STAGE1(buf)                                                            \
  do {                                                                         \
    GLD_LDS16(pA0, &As[(buf)][wave * 512]);                                    \
    GLD_LDS16(pA1, &As[(buf)][2048 + wave * 512]);                             \
    GLD_LDS16(pB0, &Bs[(buf)][wave * 512]);                                    \
    GLD_LDS16(pB1, &Bs[(buf)][2048 + wave * 512]);                             \
    pA0 += 32; pA1 += 32; pB0 += 32; pB1 += 32;                                \
  } while (0)

  STAGE1(0);
  for (int kt = 0; kt < KT; ++kt) {
    if (kt + 1 < KT) { STAGE1((kt + 1) & 1); TOPBAR_4; } else { TOPBAR_0; }
    const unsigned short* as = As[kt & 1];
    const unsigned short* bs = Bs[kt & 1];
    bf16x8 a[4], b[4];
#pragma unroll
    for (int i = 0; i < 4; ++i) a[i] = *(const bf16x8*)&as[(wr + i * 16 + fr) * 32 + koff];
#pragma unroll
    for (int j = 0; j < 4; ++j) b[j] = *(const bf16x8*)&bs[(wc + j * 16 + fr) * 32 + koff];
#pragma unroll
    for (int i = 0; i < 4; ++i)
#pragma unroll
      for (int j = 0; j < 4; ++j)
        acc[i][j] = __builtin_amdgcn_mfma_f32_16x16x32_bf16(a[i], b[j], acc[i][j], 0, 0, 0);
    BOTBAR;
  }
#undef STAGE1
  const int rbase = q * 4, cn = fr;
#pragma unroll
  for (int i = 0; i < 4; ++i)
#pragma unroll
    for (int j = 0; j < 4; ++j) {
      const int gn = n0 + wc + j * 16 + cn;
      const float bias = b1[gn];
#pragma unroll
      for (int r = 0; r < 4; ++r) {
        const int gm = m0 + wr + i * 16 + rbase + r;
        float v = acc[i][j][r] + bias;
        v = v > 0.f ? v : 0.f;
        X8[(size_t)gm * 512 + gn] = f2fp8(v * 8.f);
      }
    }
}

// ---------- GEMM2 fp8 (4 gate quadrants) + LSTM epilogue ----------
// A = X8 (x8), B = Wih8 (x16); acc * (1/128) restores scale.
__global__ __launch_bounds__(256, 4) void gemm2_lstm(
    const unsigned char* __restrict__ X8,    // [32768,512] fp8
    const unsigned char* __restrict__ Wih8,  // [2048,512] fp8
    const float* __restrict__ hvec,          // [2048]
    const float* __restrict__ cell,          // [512]
    unsigned short* __restrict__ H,          // [32768,512] bf16 out
    float* __restrict__ hlast,               // [512] fp32 out
    float* __restrict__ clast) {             // [512] fp32 out
  constexpr int KT = 16;
  __shared__ __align__(16) unsigned char As[2][128 * 32];     // 8 KB
  __shared__ __align__(16) unsigned char Bs[2][4 * 32 * 32];  // 8 KB
  const int tid = threadIdx.x, wave = tid >> 6, lane = tid & 63;
  const int id = blockIdx.x, xcd = id & 7, slot = id >> 3;  // 4096 blocks
  const int m0 = (xcd * 32 + (slot >> 4)) * 128;            // 256 m-tiles
  const int n0 = (slot & 15) * 32;                          // 16 quadrant-col tiles
  const int wr = (wave >> 1) * 64, wc = (wave & 1) * 16;
  f32x4 acc[4][4] = {};                      // [row-tile][quadrant]

  // staging: one 16B chunk per thread; c = tid; A row = c>>1, B: quad=c>>6,row=(c>>1)&31
  const int c = tid;
  const unsigned char* pA = X8 + (size_t)(m0 + (c >> 1)) * 512 + swz8(c);
  const unsigned char* pB =
      Wih8 + (size_t)((c >> 6) * 512 + n0 + ((c >> 1) & 31)) * 512 + swz8(c);
  const int fr = lane & 15, q = lane >> 4;
  const int koff = (q ^ (((fr >> 2) & 1) << 1)) * 8;  // matches 16B-half swizzle

#define STAGE2(buf)                                                            \
  do {                                                                         \
    GLD_LDS16(pA, &As[(buf)][wave * 1024]);                                    \
    GLD_LDS16(pB, &Bs[(buf)][wave * 1024]);                                    \
    pA += 32; pB += 32;                                                        \
  } while (0)

  STAGE2(0);
  for (int kt = 0; kt < KT; ++kt) {
    if (kt + 1 < KT) { STAGE2((kt + 1) & 1); TOPBAR_2; } else { TOPBAR_0; }
    const unsigned char* as = As[kt & 1];
    const unsigned char* bs = Bs[kt & 1];
    long a[4], b[4];
#pragma unroll
    for (int i = 0; i < 4; ++i) a[i] = *(const long*)&as[(wr + i * 16 + fr) * 32 + koff];
#pragma unroll
    for (int qd = 0; qd < 4; ++qd)
      b[qd] = *(const long*)&bs[qd * 1024 + (wc + fr) * 32 + koff];
#pragma unroll
    for (int i = 0; i < 4; ++i)
#pragma unroll
      for (int qd = 0; qd < 4; ++qd)
        acc[i][qd] =
            __builtin_amdgcn_mfma_f32_16x16x32_fp8_fp8(a[i], b[qd], acc[i][qd], 0, 0, 0);
    BOTBAR;
  }
#undef STAGE2
  const int rbase = q * 4, cn = fr;
  const int gn = n0 + wc + cn;  // column in [0,512)
  const float hv_i = hvec[gn];
  const float hv_f = hvec[gn + 512];
  const float hv_g = hvec[gn + 1024];
  const float hv_o = hvec[gn + 1536];
  const float cprev = cell[gn];
  constexpr float S = 1.f / 128.f;  // undo x8 (X) * x16 (Wih)
#pragma unroll
  for (int i = 0; i < 4; ++i)
#pragma unroll
    for (int r = 0; r < 4; ++r) {
      const int gm = m0 + wr + i * 16 + rbase + r;
      float si = sigm(acc[i][0][r] * S + hv_i);
      float sf = sigm(acc[i][1][r] * S + hv_f);
      float tg = tanh_(acc[i][2][r] * S + hv_g);
      float so = sigm(acc[i][3][r] * S + hv_o);
      float cnew = sf * cprev + si * tg;
      float hnew = so * tanh_(cnew);
      H[(size_t)gm * 512 + gn] = f2bf(hnew);
      if (gm == 32767) { hlast[gn] = hnew; clast[gn] = cnew; }
    }
}

// ---------- GEMM3: Q = H @ W2^T + b2 (64-row tiles, 512 blocks) ----------
__global__ __launch_bounds__(256, 2) void gemm3(
    const unsigned short* __restrict__ H,    // [32768,512] bf16
    const unsigned short* __restrict__ W2b,  // [32,512] bf16
    const float* __restrict__ b2,            // [32]
    float* __restrict__ Q) {                 // [32768,32] fp32
  constexpr int KT = 16, LDW = 520;
  __shared__ __align__(16) unsigned short As[2][64 * 32];    // 8 KB
  __shared__ __align__(16) unsigned short Ws[32 * LDW];      // 32.5 KB
  const int tid = threadIdx.x, wave = tid >> 6, lane = tid & 63;
  const int id = blockIdx.x;                                 // 512 blocks
  const int m0 = ((id & 7) * 64 + (id >> 3)) * 64;           // 64-row tiles
  for (int c = tid; c < 2048; c += 256) {
    const int row = c >> 6, col8 = c & 63;
    *(uint4*)&Ws[row * LDW + col8 * 8] = *(const uint4*)(W2b + row * 512 + col8 * 8);
  }
  f32x4 acc[2] = {};
  const int c0 = tid;
  const unsigned short* pA0 = H + (size_t)(m0 + (c0 >> 2)) * 512 + swz_col(c0);
  const int fr = lane & 15, q = lane >> 4;
  const int koff = (q ^ ((fr >> 1) & 3)) * 8;

#define STAGE3(buf)                                                            \
  do {                                                                         \
    GLD_LDS16(pA0, &As[(buf)][wave * 512]);                                    \
    pA0 += 32;                                                                 \
  } while (0)

  STAGE3(0);
  for (int kt = 0; kt < KT; ++kt) {
    if (kt + 1 < KT) { STAGE3((kt + 1) & 1); TOPBAR_1; } else { TOPBAR_0; }
    const unsigned short* as = As[kt & 1];
    const int k0 = kt * 32;
    bf16x8 a  = *(const bf16x8*)&as[(wave * 16 + fr) * 32 + koff];
    bf16x8 b0 = *(const bf16x8*)&Ws[fr * LDW + k0 + q * 8];
    bf16x8 b1 = *(const bf16x8*)&Ws[(16 + fr) * LDW + k0 + q * 8];
    acc[0] = __builtin_amdgcn_mfma_f32_16x16x32_bf16(a, b0, acc[0], 0, 0, 0);
    acc[1] = __builtin_amdgcn_mfma_f32_16x16x32_bf16(a, b1, acc[1], 0, 0, 0);
    BOTBAR;
  }
#undef STAGE3
  const int rbase = q * 4;
#pragma unroll
  for (int j = 0; j < 2; ++j) {
    const int gn = j * 16 + fr;
    const float bias = b2[gn];
#pragma unroll
    for (int r = 0; r < 4; ++r) {
      const int gm = m0 + wave * 16 + rbase + r;
      Q[(size_t)gm * 32 + gn] = acc[j][r] + bias;
    }
  }
}

// ---------- launch ----------
extern "C" void kernel_launch(void* const* d_in, const int* in_sizes, int n_in,
                              void* d_out, int out_size, void* d_ws, size_t ws_size,
                              hipStream_t stream) {
  const float* obs  = (const float*)d_in[0];
  const float* act  = (const float*)d_in[1];
  const float* hid  = (const float*)d_in[2];
  const float* cell = (const float*)d_in[3];
  const float* W1   = (const float*)d_in[4];
  const float* b1   = (const float*)d_in[5];
  const float* Wih  = (const float*)d_in[6];
  const float* bih  = (const float*)d_in[7];
  const float* Whh  = (const float*)d_in[8];
  const float* bhh  = (const float*)d_in[9];
  const float* W2   = (const float*)d_in[10];
  const float* b2   = (const float*)d_in[11];
  float* out = (float*)d_out;

  char* ws = (char*)d_ws;
  unsigned short* A0   = (unsigned short*)(ws);              // [B,544] bf16 (35,651,584 B)
  unsigned short* H    = (unsigned short*)(ws);              // alias A0 (dead after gemm1)
  unsigned char*  X8   = (unsigned char*)(ws + 35651584);    // [B,512] fp8 (16,777,216 B)
  unsigned short* W1b  = (unsigned short*)(ws + 52428800);   // 557,056 B
  unsigned char*  Wih8 = (unsigned char*)(ws + 52985856);    // 1,048,576 B
  unsigned short* W2b  = (unsigned short*)(ws + 54034432);   // 32,768 B
  float*          hvec = (float*)(ws + 54067200);            // 8,192 B

  prep_all<<<4000, 256, 0, stream>>>(obs, act, W1, Wih, W2, Whh, hid, bhh, bih,
                                     A0, W1b, Wih8, W2b, hvec);
  gemm1_relu<<<1024, 256, 0, stream>>>(A0, W1b, b1, X8);
  gemm2_lstm<<<4096, 256, 0, stream>>>(X8, Wih8, hvec, cell, H,
                                       out + 32768 * 32,
                                       out + 32768 * 32 + 512);
  gemm3<<<512, 256, 0, stream>>>(H, W2b, b2, out);
}

// Round 8
// 213.254 us; speedup vs baseline: 1.3120x; 1.1228x over previous
//
#include <hip/hip_runtime.h>
#include <stdint.h>

#define DEVINL __device__ __forceinline__

typedef __attribute__((ext_vector_type(8))) __bf16 bf16x8;
typedef __attribute__((ext_vector_type(4))) float f32x4;
typedef __attribute__((ext_vector_type(2))) long longx2;

// ---------- helpers ----------
DEVINL unsigned short f2bf(float f) {
  union { float f; unsigned int u; } v; v.f = f;
  unsigned int u = v.u;
  return (unsigned short)((u + 0x7fffu + ((u >> 16) & 1u)) >> 16);  // RNE
}

// float -> OCP e4m3 byte via HW cvt (gfx950 = OCP semantics)
DEVINL unsigned char f2fp8(float f) {
  return (unsigned char)(__builtin_amdgcn_cvt_pk_fp8_f32(f, f, 0, false) & 0xff);
}

DEVINL float sigm(float x) { return __builtin_amdgcn_rcpf(1.f + __expf(-x)); }
// tanh = 1 - 2/(1+e^{2x}); inf-safe both directions.
DEVINL float tanh_(float x) {
  return 1.f - 2.f * __builtin_amdgcn_rcpf(1.f + __expf(2.f * x));
}

// K-window interleave for fp8 BK=64 tiles: within each 64-col window,
// element k sits at byte ((k&31)>>3)*16 + (k>>5)*8 + (k&7).
// -> 16B chunk q holds [k=8q..8q+7 | k=32+8q..32+8q+7]; a b128 read gives a
// lane both 8B MFMA operands (k-lo, k-hi) for its quad q.
DEVINL int pcol(int gn) {
  return (gn & ~63) | ((((gn & 31) >> 3)) << 4) | (((gn >> 5) & 1) << 3) | (gn & 7);
}

// async global->LDS 16B per lane; lds base wave-uniform, HW scatters lane i to base+i*16
#define GLD_LDS16(gptr, lptr)                                                  \
  __builtin_amdgcn_global_load_lds(                                            \
      (__attribute__((address_space(1))) void*)(gptr),                         \
      (__attribute__((address_space(3))) void*)(lptr), 16, 0, 0)

// Stage-before-barrier pipeline: STAGE(k+1) issued BEFORE the top barrier;
// TOPBAR_N waits vmcnt(N) = one stage's loads -> stage k landed, stage k+1
// crosses the barrier in flight. Last iter peels to vmcnt(0).
#define TOPBAR_4 asm volatile("s_waitcnt vmcnt(4) lgkmcnt(0)\n\ts_barrier" ::: "memory")
#define TOPBAR_1 asm volatile("s_waitcnt vmcnt(1) lgkmcnt(0)\n\ts_barrier" ::: "memory")
#define TOPBAR_0 asm volatile("s_waitcnt vmcnt(0) lgkmcnt(0)\n\ts_barrier" ::: "memory")
#define BOTBAR   asm volatile("s_waitcnt lgkmcnt(0)\n\ts_barrier" ::: "memory")

// XOR swizzle, 16B chunks, 4 chunks/row: staging chunk c (row=c>>2) takes
// source chunk (c&3)^((c>>3)&3). Verified zero-conflict with the matching
// read-side koff = (q ^ ((fr>>1)&3)) (R3, bf16).
DEVINL int swz_col(int c) { return ((c & 3) ^ ((c >> 3) & 3)) * 8; }   // bf16: *8 shorts = 16B
DEVINL int swz16(int c) { return ((c & 3) ^ ((c >> 3) & 3)) * 16; }    // fp8: byte offset

// ---------- fused prep: input concat + weight cvt + hvec, grid-sectioned ----------
__global__ void prep_all(const float* __restrict__ obs, const float* __restrict__ act,
                         const float* __restrict__ W1, const float* __restrict__ Wih,
                         const float* __restrict__ W2, const float* __restrict__ Whh,
                         const float* __restrict__ hid, const float* __restrict__ bhh,
                         const float* __restrict__ bih,
                         unsigned short* __restrict__ A0, unsigned short* __restrict__ W1b,
                         unsigned char* __restrict__ Wih8, unsigned short* __restrict__ W2b,
                         float* __restrict__ hvec) {
  const int bid = blockIdx.x, tid = threadIdx.x;
  if (bid < 2176) {
    // section A: concat(obs, act) -> bf16 [32768, 544]
    const int total = 32768 * 68;
    for (int c = bid * 256 + tid; c < total; c += 2176 * 256) {
      const int b = c / 68, c8 = c % 68;
      const float* src = (c8 < 64) ? (obs + (size_t)b * 512 + c8 * 8)
                                   : (act + (size_t)b * 32 + (c8 - 64) * 8);
      float4 f0 = *(const float4*)src;
      float4 f1 = *(const float4*)(src + 4);
      unsigned short u[8] = {f2bf(f0.x), f2bf(f0.y), f2bf(f0.z), f2bf(f0.w),
                             f2bf(f1.x), f2bf(f1.y), f2bf(f1.z), f2bf(f1.w)};
      *(uint4*)(A0 + (size_t)b * 544 + c8 * 8) = *(uint4*)u;
    }
  } else if (bid < 2176 + 1312) {
    // section B: weight conversion (one float4 per thread)
    const int i = (bid - 2176) * 256 + tid;
    if (i < 69632) {                       // W1 -> bf16
      float4 f = *(const float4*)(W1 + (size_t)i * 4);
      unsigned short u[4] = {f2bf(f.x), f2bf(f.y), f2bf(f.z), f2bf(f.w)};
      *(uint2*)(W1b + (size_t)i * 4) = *(uint2*)u;
    } else if (i < 69632 + 262144) {       // Wih -> fp8 e4m3 x16, K-interleaved layout
      const int off = i - 69632;
      const int row = off >> 7, col0 = (off & 127) * 4;  // 4 consecutive cols, same 8-group
      float4 f = *(const float4*)(Wih + (size_t)off * 4);
      int pk = __builtin_amdgcn_cvt_pk_fp8_f32(f.x * 16.f, f.y * 16.f, 0, false);
      pk = __builtin_amdgcn_cvt_pk_fp8_f32(f.z * 16.f, f.w * 16.f, pk, true);
      *(unsigned int*)(Wih8 + (size_t)row * 512 + pcol(col0)) = (unsigned int)pk;
    } else {                               // W2 -> bf16
      const int off = i - 331776;
      float4 f = *(const float4*)(W2 + (size_t)off * 4);
      unsigned short u[4] = {f2bf(f.x), f2bf(f.y), f2bf(f.z), f2bf(f.w)};
      *(uint2*)(W2b + (size_t)off * 4) = *(uint2*)u;
    }
  } else {
    // section C: hvec[j] = dot(W_hh[j,:], hid) + b_hh[j] + b_ih[j]
    const int j = (bid - 3488) * 4 + (tid >> 6);
    const int lane = tid & 63;
    const float* w = Whh + (size_t)j * 512;
    float s = 0.f;
    for (int k = lane; k < 512; k += 64) s += w[k] * hid[k];
    for (int off = 32; off; off >>= 1) s += __shfl_down(s, off, 64);
    if (lane == 0) hvec[j] = s + bhh[j] + bih[j];
  }
}

// ---------- GEMM1: X8 = fp8(relu(A0 @ W1^T + b1) * 8), K-interleaved ----------
__global__ __launch_bounds__(256, 2) void gemm1_relu(
    const unsigned short* __restrict__ A0,   // [32768,544] bf16
    const unsigned short* __restrict__ W1b,  // [512,544] bf16
    const float* __restrict__ b1,            // [512]
    unsigned char* __restrict__ X8) {        // [32768,512] fp8 (x8, K-interleaved)
  constexpr int KT = 17, LD = 544;
  __shared__ __align__(16) unsigned short As[2][128 * 32];  // 16 KB
  __shared__ __align__(16) unsigned short Bs[2][128 * 32];  // 16 KB
  const int tid = threadIdx.x, wave = tid >> 6, lane = tid & 63;
  const int id = blockIdx.x, xcd = id & 7, slot = id >> 3;  // 1024 blocks
  const int m0 = (xcd * 32 + (slot >> 2)) * 128;            // 256 m-tiles
  const int n0 = (slot & 3) * 128;                          // 4 n-tiles
  const int wr = (wave >> 1) * 64, wc = (wave & 1) * 64;
  f32x4 acc[4][4] = {};

  const int c0 = tid, c1 = tid + 256;
  const unsigned short* pA0 = A0 + (size_t)(m0 + (c0 >> 2)) * LD + swz_col(c0);
  const unsigned short* pA1 = A0 + (size_t)(m0 + (c1 >> 2)) * LD + swz_col(c1);
  const unsigned short* pB0 = W1b + (size_t)(n0 + (c0 >> 2)) * LD + swz_col(c0);
  const unsigned short* pB1 = W1b + (size_t)(n0 + (c1 >> 2)) * LD + swz_col(c1);
  const int fr = lane & 15, q = lane >> 4;
  const int koff = (q ^ ((fr >> 1) & 3)) * 8;

#define STAGE1(buf)                                                            \
  do {                                                                         \
    GLD_LDS16(pA0, &As[(buf)][wave * 512]);                                    \
    GLD_LDS16(pA1, &As[(buf)][2048 + wave * 512]);                             \
    GLD_LDS16(pB0, &Bs[(buf)][wave * 512]);                                    \
    GLD_LDS16(pB1, &Bs[(buf)][2048 + wave * 512]);                             \
    pA0 += 32; pA1 += 32; pB0 += 32; pB1 += 32;                                \
  } while (0)

  STAGE1(0);
  for (int kt = 0; kt < KT; ++kt) {
    if (kt + 1 < KT) { STAGE1((kt + 1) & 1); TOPBAR_4; } else { TOPBAR_0; }
    const unsigned short* as = As[kt & 1];
    const unsigned short* bs = Bs[kt & 1];
    bf16x8 a[4], b[4];
#pragma unroll
    for (int i = 0; i < 4; ++i) a[i] = *(const bf16x8*)&as[(wr + i * 16 + fr) * 32 + koff];
#pragma unroll
    for (int j = 0; j < 4; ++j) b[j] = *(const bf16x8*)&bs[(wc + j * 16 + fr) * 32 + koff];
#pragma unroll
    for (int i = 0; i < 4; ++i)
#pragma unroll
      for (int j = 0; j < 4; ++j)
        acc[i][j] = __builtin_amdgcn_mfma_f32_16x16x32_bf16(a[i], b[j], acc[i][j], 0, 0, 0);
    BOTBAR;
  }
#undef STAGE1
  const int rbase = q * 4, cn = fr;
#pragma unroll
  for (int i = 0; i < 4; ++i)
#pragma unroll
    for (int j = 0; j < 4; ++j) {
      const int gn = n0 + wc + j * 16 + cn;
      const int pc = pcol(gn);  // K-interleaved column for gemm2's BK=64 tiles
      const float bias = b1[gn];
#pragma unroll
      for (int r = 0; r < 4; ++r) {
        const int gm = m0 + wr + i * 16 + rbase + r;
        float v = acc[i][j][r] + bias;
        v = v > 0.f ? v : 0.f;
        X8[(size_t)gm * 512 + pc] = f2fp8(v * 8.f);
      }
    }
}

// ---------- GEMM2 fp8 BK=64 (4 gate quadrants) + LSTM epilogue ----------
// A = X8 (x8), B = Wih8 (x16), both K-interleaved; acc * (1/128) restores scale.
__global__ __launch_bounds__(256, 4) void gemm2_lstm(
    const unsigned char* __restrict__ X8,    // [32768,512] fp8, K-interleaved
    const unsigned char* __restrict__ Wih8,  // [2048,512] fp8, K-interleaved
    const float* __restrict__ hvec,          // [2048]
    const float* __restrict__ cell,          // [512]
    unsigned short* __restrict__ H,          // [32768,512] bf16 out
    float* __restrict__ hlast,               // [512] fp32 out
    float* __restrict__ clast) {             // [512] fp32 out
  constexpr int KT = 8;                      // BK = 64
  __shared__ __align__(16) unsigned char As[2][128 * 64];     // 8 KB each buf
  __shared__ __align__(16) unsigned char Bs[2][4 * 32 * 64];  // 8 KB each buf
  const int tid = threadIdx.x, wave = tid >> 6, lane = tid & 63;
  const int id = blockIdx.x, xcd = id & 7, slot = id >> 3;  // 4096 blocks
  const int m0 = (xcd * 32 + (slot >> 4)) * 128;            // 256 m-tiles
  const int n0 = (slot & 15) * 32;                          // 16 quadrant-col tiles
  const int wr = (wave >> 1) * 64, wc = (wave & 1) * 16;
  f32x4 acc[4][4] = {};                      // [row-tile][quadrant]

  // A tile: 128 rows x 64B = 512 chunks; B: 4 quads x 32 rows x 64B = 512 chunks.
  // chunk c: A row = c>>2; B quad = c>>7, row = (c>>2)&31; col swizzle = swz16(c).
  const int c0 = tid, c1 = tid + 256;
  const unsigned char* pA0 = X8 + (size_t)(m0 + (c0 >> 2)) * 512 + swz16(c0);
  const unsigned char* pA1 = X8 + (size_t)(m0 + (c1 >> 2)) * 512 + swz16(c1);
  const unsigned char* pB0 =
      Wih8 + (size_t)((c0 >> 7) * 512 + n0 + ((c0 >> 2) & 31)) * 512 + swz16(c0);
  const unsigned char* pB1 =
      Wih8 + (size_t)((c1 >> 7) * 512 + n0 + ((c1 >> 2) & 31)) * 512 + swz16(c1);
  const int fr = lane & 15, q = lane >> 4;
  const int koff = (q ^ ((fr >> 1) & 3)) * 16;  // matches swz16 (zero-conflict, R3 structure)

#define STAGE2(buf)                                                            \
  do {                                                                         \
    GLD_LDS16(pA0, &As[(buf)][wave * 1024]);                                   \
    GLD_LDS16(pA1, &As[(buf)][4096 + wave * 1024]);                            \
    GLD_LDS16(pB0, &Bs[(buf)][wave * 1024]);                                   \
    GLD_LDS16(pB1, &Bs[(buf)][4096 + wave * 1024]);                            \
    pA0 += 64; pA1 += 64; pB0 += 64; pB1 += 64;                                \
  } while (0)

  STAGE2(0);
  for (int kt = 0; kt < KT; ++kt) {
    if (kt + 1 < KT) { STAGE2((kt + 1) & 1); TOPBAR_4; } else { TOPBAR_0; }
    const unsigned char* as = As[kt & 1];
    const unsigned char* bs = Bs[kt & 1];
    longx2 a[4], b[4];  // .x = k 0..31 operand, .y = k 32..63 operand
#pragma unroll
    for (int i = 0; i < 4; ++i)
      a[i] = *(const longx2*)&as[(wr + i * 16 + fr) * 64 + koff];
#pragma unroll
    for (int qd = 0; qd < 4; ++qd)
      b[qd] = *(const longx2*)&bs[qd * 2048 + (wc + fr) * 64 + koff];
#pragma unroll
    for (int i = 0; i < 4; ++i)
#pragma unroll
      for (int qd = 0; qd < 4; ++qd) {
        acc[i][qd] =
            __builtin_amdgcn_mfma_f32_16x16x32_fp8_fp8(a[i].x, b[qd].x, acc[i][qd], 0, 0, 0);
        acc[i][qd] =
            __builtin_amdgcn_mfma_f32_16x16x32_fp8_fp8(a[i].y, b[qd].y, acc[i][qd], 0, 0, 0);
      }
    BOTBAR;
  }
#undef STAGE2
  const int rbase = q * 4, cn = fr;
  const int gn = n0 + wc + cn;  // column in [0,512)
  const float hv_i = hvec[gn];
  const float hv_f = hvec[gn + 512];
  const float hv_g = hvec[gn + 1024];
  const float hv_o = hvec[gn + 1536];
  const float cprev = cell[gn];
  constexpr float S = 1.f / 128.f;  // undo x8 (X) * x16 (Wih)
#pragma unroll
  for (int i = 0; i < 4; ++i)
#pragma unroll
    for (int r = 0; r < 4; ++r) {
      const int gm = m0 + wr + i * 16 + rbase + r;
      float si = sigm(acc[i][0][r] * S + hv_i);
      float sf = sigm(acc[i][1][r] * S + hv_f);
      float tg = tanh_(acc[i][2][r] * S + hv_g);
      float so = sigm(acc[i][3][r] * S + hv_o);
      float cnew = sf * cprev + si * tg;
      float hnew = so * tanh_(cnew);
      H[(size_t)gm * 512 + gn] = f2bf(hnew);
      if (gm == 32767) { hlast[gn] = hnew; clast[gn] = cnew; }
    }
}

// ---------- GEMM3: Q = H @ W2^T + b2 (64-row tiles, 512 blocks) ----------
__global__ __launch_bounds__(256, 2) void gemm3(
    const unsigned short* __restrict__ H,    // [32768,512] bf16
    const unsigned short* __restrict__ W2b,  // [32,512] bf16
    const float* __restrict__ b2,            // [32]
    float* __restrict__ Q) {                 // [32768,32] fp32
  constexpr int KT = 16, LDW = 520;
  __shared__ __align__(16) unsigned short As[2][64 * 32];    // 8 KB
  __shared__ __align__(16) unsigned short Ws[32 * LDW];      // 32.5 KB
  const int tid = threadIdx.x, wave = tid >> 6, lane = tid & 63;
  const int id = blockIdx.x;                                 // 512 blocks
  const int m0 = ((id & 7) * 64 + (id >> 3)) * 64;           // 64-row tiles
  for (int c = tid; c < 2048; c += 256) {
    const int row = c >> 6, col8 = c & 63;
    *(uint4*)&Ws[row * LDW + col8 * 8] = *(const uint4*)(W2b + row * 512 + col8 * 8);
  }
  f32x4 acc[2] = {};
  const int c0 = tid;
  const unsigned short* pA0 = H + (size_t)(m0 + (c0 >> 2)) * 512 + swz_col(c0);
  const int fr = lane & 15, q = lane >> 4;
  const int koff = (q ^ ((fr >> 1) & 3)) * 8;

#define STAGE3(buf)                                                            \
  do {                                                                         \
    GLD_LDS16(pA0, &As[(buf)][wave * 512]);                                    \
    pA0 += 32;                                                                 \
  } while (0)

  STAGE3(0);
  for (int kt = 0; kt < KT; ++kt) {
    if (kt + 1 < KT) { STAGE3((kt + 1) & 1); TOPBAR_1; } else { TOPBAR_0; }
    const unsigned short* as = As[kt & 1];
    const int k0 = kt * 32;
    bf16x8 a  = *(const bf16x8*)&as[(wave * 16 + fr) * 32 + koff];
    bf16x8 b0 = *(const bf16x8*)&Ws[fr * LDW + k0 + q * 8];
    bf16x8 b1 = *(const bf16x8*)&Ws[(16 + fr) * LDW + k0 + q * 8];
    acc[0] = __builtin_amdgcn_mfma_f32_16x16x32_bf16(a, b0, acc[0], 0, 0, 0);
    acc[1] = __builtin_amdgcn_mfma_f32_16x16x32_bf16(a, b1, acc[1], 0, 0, 0);
    BOTBAR;
  }
#undef STAGE3
  const int rbase = q * 4;
#pragma unroll
  for (int j = 0; j < 2; ++j) {
    const int gn = j * 16 + fr;
    const float bias = b2[gn];
#pragma unroll
    for (int r = 0; r < 4; ++r) {
      const int gm = m0 + wave * 16 + rbase + r;
      Q[(size_t)gm * 32 + gn] = acc[j][r] + bias;
    }
  }
}

// ---------- launch ----------
extern "C" void kernel_launch(void* const* d_in, const int* in_sizes, int n_in,
                              void* d_out, int out_size, void* d_ws, size_t ws_size,
                              hipStream_t stream) {
  const float* obs  = (const float*)d_in[0];
  const float* act  = (const float*)d_in[1];
  const float* hid  = (const float*)d_in[2];
  const float* cell = (const float*)d_in[3];
  const float* W1   = (const float*)d_in[4];
  const float* b1   = (const float*)d_in[5];
  const float* Wih  = (const float*)d_in[6];
  const float* bih  = (const float*)d_in[7];
  const float* Whh  = (const float*)d_in[8];
  const float* bhh  = (const float*)d_in[9];
  const float* W2   = (const float*)d_in[10];
  const float* b2   = (const float*)d_in[11];
  float* out = (float*)d_out;

  char* ws = (char*)d_ws;
  unsigned short* A0   = (unsigned short*)(ws);              // [B,544] bf16 (35,651,584 B)
  unsigned short* H    = (unsigned short*)(ws);              // alias A0 (dead after gemm1)
  unsigned char*  X8   = (unsigned char*)(ws + 35651584);    // [B,512] fp8 (16,777,216 B)
  unsigned short* W1b  = (unsigned short*)(ws + 52428800);   // 557,056 B
  unsigned char*  Wih8 = (unsigned char*)(ws + 52985856);    // 1,048,576 B
  unsigned short* W2b  = (unsigned short*)(ws + 54034432);   // 32,768 B
  float*          hvec = (float*)(ws + 54067200);            // 8,192 B

  prep_all<<<4000, 256, 0, stream>>>(obs, act, W1, Wih, W2, Whh, hid, bhh, bih,
                                     A0, W1b, Wih8, W2b, hvec);
  gemm1_relu<<<1024, 256, 0, stream>>>(A0, W1b, b1, X8);
  gemm2_lstm<<<4096, 256, 0, stream>>>(X8, Wih8, hvec, cell, H,
                                       out + 32768 * 32,
                                       out + 32768 * 32 + 512);
  gemm3<<<512, 256, 0, stream>>>(H, W2b, b2, out);
}